// Round 7
// baseline (429.686 us; speedup 1.0000x reference)
//
#include <hip/hip_runtime.h>
#include <math.h>

#define L_SEQ   2048
#define DM      1024
#define DI      2048
#define NST     16
#define LC      32      // chunk length for scan
#define NCHUNK  64      // L_SEQ / LC
#define XP_LD   36      // padded leading dim for xp (33 cols)
#define KSPLIT  8       // K-splits for gemm_xp

typedef short s16x8 __attribute__((ext_vector_type(8)));
typedef float f32x4 __attribute__((ext_vector_type(4)));

__device__ __forceinline__ float silu_f(float x) {
  return x / (1.0f + __expf(-x));
}
__device__ __forceinline__ float softplus_f(float x) {
  return x > 20.0f ? x : log1pf(__expf(x));
}
// fp32 -> bf16 RNE
__device__ __forceinline__ ushort f2bf(float f) {
  unsigned int u = __float_as_uint(f);
  unsigned int r = (u + 0x7fffu + ((u >> 16) & 1u)) >> 16;
  return (ushort)r;
}
__device__ __forceinline__ void gload_lds16(const void* g, void* lds) {
  __builtin_amdgcn_global_load_lds(
      (const __attribute__((address_space(1))) unsigned int*)g,
      (__attribute__((address_space(3))) unsigned int*)lds,
      16, 0, 0);
}

// ---------------------------------------------------------------------------
// fp32 -> bf16 conversion, 4 elems/thread
// ---------------------------------------------------------------------------
__global__ __launch_bounds__(256) void cvt_bf16_k(
    const float* __restrict__ in, ushort* __restrict__ out, int n4) {
  int i = blockIdx.x * 256 + threadIdx.x;
  if (i >= n4) return;
  float4 v = ((const float4*)in)[i];
  ushort4 o;
  o.x = f2bf(v.x); o.y = f2bf(v.y); o.z = f2bf(v.z); o.w = f2bf(v.w);
  ((ushort4*)out)[i] = o;
}

// ---------------------------------------------------------------------------
// bf16 MFMA GEMM: C(MxN fp32) = A(MxK bf16,row-major) * B(NxK bf16,row-major)^T
// m97 structure: BK=32, 256 thr = 4 waves (2x2), wave tile = MFRAG*16 x 64.
// BM = MFRAG*32, BN = 128.  grid = (N/128, M/BM).
// ---------------------------------------------------------------------------
template <int MFRAG>
__global__ __launch_bounds__(256) void gemm_mfma_bf16(
    const ushort* __restrict__ A, const ushort* __restrict__ B,
    float* __restrict__ C, int K, int ldc) {
  constexpr int BM = MFRAG * 32;
  __shared__ ushort As[BM * 32];
  __shared__ ushort Bs[128 * 32];
  const int tid  = threadIdx.x;
  const int lane = tid & 63;
  const int wv   = tid >> 6;
  const int wr   = wv >> 1;   // wave row 0..1
  const int wc   = wv & 1;    // wave col 0..1
  const int m0 = blockIdx.y * BM;
  const int n0 = blockIdx.x * 128;

  f32x4 acc[MFRAG][4] = {};

  const int kc = (tid & 3) * 8;   // bf16-element offset of this thread's 16B chunk

  for (int k0 = 0; k0 < K; k0 += 32) {
    __syncthreads();
    // stage A tile: BM rows x 32 cols bf16 = BM*4 chunks of 16B
#pragma unroll
    for (int q = 0; q < BM / 64; ++q) {
      int id = q * 256 + tid;
      int m  = id >> 2;
      gload_lds16(A + (size_t)(m0 + m) * K + k0 + kc, (char*)As + id * 16);
    }
    // stage B tile: 128 rows x 32 cols
#pragma unroll
    for (int q = 0; q < 2; ++q) {
      int id = q * 256 + tid;
      int n  = id >> 2;
      gload_lds16(B + (size_t)(n0 + n) * K + k0 + kc, (char*)Bs + id * 16);
    }
    __syncthreads();   // drains vmcnt before reads

    s16x8 af[MFRAG], bfr[4];
#pragma unroll
    for (int m = 0; m < MFRAG; ++m)
      af[m] = *(const s16x8*)&As[(wr * MFRAG * 16 + m * 16 + (lane & 15)) * 32 + (lane >> 4) * 8];
#pragma unroll
    for (int n = 0; n < 4; ++n)
      bfr[n] = *(const s16x8*)&Bs[(wc * 64 + n * 16 + (lane & 15)) * 32 + (lane >> 4) * 8];
#pragma unroll
    for (int m = 0; m < MFRAG; ++m)
#pragma unroll
      for (int n = 0; n < 4; ++n)
        acc[m][n] = __builtin_amdgcn_mfma_f32_16x16x32_bf16(af[m], bfr[n], acc[m][n], 0, 0, 0);
  }
  // epilogue: C/D layout col=lane&15, row=(lane>>4)*4+reg  [m89-verified]
  const int cr = (lane >> 4) * 4;
  const int cc = lane & 15;
#pragma unroll
  for (int m = 0; m < MFRAG; ++m) {
    int gr0 = m0 + wr * MFRAG * 16 + m * 16 + cr;
#pragma unroll
    for (int n = 0; n < 4; ++n) {
      int gc = n0 + wc * 64 + n * 16 + cc;
#pragma unroll
      for (int r = 0; r < 4; ++r)
        C[(size_t)(gr0 + r) * ldc + gc] = acc[m][n][r];
    }
  }
}

// ---------------------------------------------------------------------------
// Depthwise causal conv (D_CONV=4) + bias + silu.  Writes xc (l,d) row-major.
// ---------------------------------------------------------------------------
__global__ __launch_bounds__(256) void conv_silu_k(
    const float* __restrict__ xz, const float* __restrict__ cw,
    const float* __restrict__ cb, float* __restrict__ xc) {
  const int d = blockIdx.x * 256 + threadIdx.x;
  const int l = blockIdx.y;
  const float w0 = cw[d*4+0], w1 = cw[d*4+1], w2 = cw[d*4+2], w3 = cw[d*4+3];
  float acc = cb[d];
  if (l >= 3) acc = fmaf(w0, xz[(size_t)(l-3)*4096 + d], acc);
  if (l >= 2) acc = fmaf(w1, xz[(size_t)(l-2)*4096 + d], acc);
  if (l >= 1) acc = fmaf(w2, xz[(size_t)(l-1)*4096 + d], acc);
  acc = fmaf(w3, xz[(size_t)l*4096 + d], acc);
  xc[(size_t)l*DI + d] = silu_f(acc);
}

// ---------------------------------------------------------------------------
// 64x64 LDS-tiled transpose: xcT[d][l] = xc[l][d].  grid (DI/64, L/64).
// ---------------------------------------------------------------------------
__global__ __launch_bounds__(256) void transpose_k(
    const float* __restrict__ in, float* __restrict__ out) {
  __shared__ float tile[64][65];
  const int d0 = blockIdx.x * 64, l0 = blockIdx.y * 64;
  const int r  = threadIdx.x >> 4;
  const int c4 = (threadIdx.x & 15) * 4;
#pragma unroll
  for (int p = 0; p < 4; ++p) {
    float4 v = *(const float4*)&in[(size_t)(l0 + r + p*16) * DI + d0 + c4];
    tile[r + p*16][c4+0] = v.x; tile[r + p*16][c4+1] = v.y;
    tile[r + p*16][c4+2] = v.z; tile[r + p*16][c4+3] = v.w;
  }
  __syncthreads();
  const int dd = threadIdx.x >> 4;
  const int l4 = (threadIdx.x & 15) * 4;
#pragma unroll
  for (int p = 0; p < 4; ++p) {
    float4 v;
    v.x = tile[l4+0][dd + p*16];
    v.y = tile[l4+1][dd + p*16];
    v.z = tile[l4+2][dd + p*16];
    v.w = tile[l4+3][dd + p*16];
    *(float4*)&out[(size_t)(d0 + dd + p*16) * L_SEQ + l0 + l4] = v;
  }
}

// ---------------------------------------------------------------------------
// xp partials: split-K over KSPLIT slices of 256.
// grid = (L/64, KSPLIT).  Per block: 64 rows x 33 cols, K-slice 256.
// ---------------------------------------------------------------------------
__global__ __launch_bounds__(256) void gemm_xp_k(
    const float* __restrict__ xc, const float* __restrict__ Wxp,
    float* __restrict__ xp_part) {
  const int L0   = blockIdx.x * 64;
  const int ks   = blockIdx.y;
  const int wv   = threadIdx.x >> 6;
  const int lane = threadIdx.x & 63;
  __shared__ float xcs[64][65];
  __shared__ float Ws[36][64];
  float acc[9] = {};
  const int kbeg = ks * (DI / KSPLIT);
  const int kend = kbeg + DI / KSPLIT;
  for (int k0 = kbeg; k0 < kend; k0 += 64) {
    {
      int r = threadIdx.x >> 2;
      int cbase = (threadIdx.x & 3) * 16;
#pragma unroll
      for (int q = 0; q < 4; ++q) {
        float4 v = *(const float4*)&xc[(size_t)(L0 + r) * DI + k0 + cbase + q*4];
        xcs[r][cbase + q*4 + 0] = v.x; xcs[r][cbase + q*4 + 1] = v.y;
        xcs[r][cbase + q*4 + 2] = v.z; xcs[r][cbase + q*4 + 3] = v.w;
      }
    }
    for (int idx = threadIdx.x; idx < 36 * 16; idx += 256) {
      int j = idx >> 4; int cc = (idx & 15) << 2;
      float4 v = make_float4(0.f, 0.f, 0.f, 0.f);
      if (j < 33) v = *(const float4*)&Wxp[(size_t)j * DI + k0 + cc];
      *(float4*)&Ws[j][cc] = v;
    }
    __syncthreads();
#pragma unroll 4
    for (int kk = 0; kk < 64; kk += 4) {
      float4 wr[9];
#pragma unroll
      for (int jj = 0; jj < 9; ++jj) wr[jj] = *(const float4*)&Ws[wv*9 + jj][kk];
      float a0 = xcs[lane][kk+0], a1 = xcs[lane][kk+1];
      float a2 = xcs[lane][kk+2], a3 = xcs[lane][kk+3];
#pragma unroll
      for (int jj = 0; jj < 9; ++jj) {
        acc[jj] = fmaf(a0, wr[jj].x, acc[jj]);
        acc[jj] = fmaf(a1, wr[jj].y, acc[jj]);
        acc[jj] = fmaf(a2, wr[jj].z, acc[jj]);
        acc[jj] = fmaf(a3, wr[jj].w, acc[jj]);
      }
    }
    __syncthreads();
  }
  const int l = L0 + lane;
#pragma unroll
  for (int jj = 0; jj < 9; ++jj) {
    int j = wv * 9 + jj;
    if (j < 33)
      xp_part[(size_t)ks * L_SEQ * XP_LD + (size_t)l * XP_LD + j] = acc[jj];
  }
}

// ---------------------------------------------------------------------------
// Reduce split-K partials: xp = sum_ks xp_part[ks].
// ---------------------------------------------------------------------------
__global__ __launch_bounds__(256) void reduce_xp_k(
    const float* __restrict__ part, float* __restrict__ xp) {
  int i = blockIdx.x * 256 + threadIdx.x;
  float s = 0.f;
#pragma unroll
  for (int ks = 0; ks < KSPLIT; ++ks)
    s += part[(size_t)ks * L_SEQ * XP_LD + i];
  xp[i] = s;
}

// ---------------------------------------------------------------------------
// LDS staging for scan: xps row = [B 0..15 | C 16..31 | dtr 32], stride 36
// (16B-aligned vector reads, wave-uniform -> broadcast).
// ---------------------------------------------------------------------------
__device__ __forceinline__ void stage_xps(
    float (*xps)[36], const float* __restrict__ xp, int l0, int tid) {
  for (int idx = tid; idx < LC * 33; idx += 256) {
    int rr = idx / 33, j = idx - rr * 33;
    int col = (j == 0) ? 32 : j - 1;
    xps[rr][col] = xp[(size_t)(l0 + rr) * XP_LD + j];
  }
}

// ---------------------------------------------------------------------------
// Scan phase A: per-chunk local scan from h=0, n-split x2 (8 states/thread).
// xcT is (d, l) so each thread's chunk is contiguous -> register prefetch.
// Emits P = prod(dA), Q = h_end.  grid = (DI/128, NCHUNK), 256 thr.
// ---------------------------------------------------------------------------
__global__ __launch_bounds__(256) void scan_partial_k(
    const float* __restrict__ xcT, const float* __restrict__ xp,
    const float* __restrict__ dtw, const float* __restrict__ dtb,
    const float* __restrict__ A_log,
    float* __restrict__ P, float* __restrict__ Q) {
  const int tid = threadIdx.x;
  const int d   = blockIdx.x * 128 + (tid >> 1);
  const int nb  = (tid & 1) * 8;
  const int c   = blockIdx.y;
  const int l0  = c * LC;
  __shared__ float xps[LC][36];
  stage_xps(xps, xp, l0, tid);

  // register prefetch: whole chunk of xc (contiguous in xcT)
  float xcf[LC];
  {
    const float4* src = (const float4*)(xcT + (size_t)d * L_SEQ + l0);
#pragma unroll
    for (int q = 0; q < LC/4; ++q) *(float4*)&xcf[q*4] = src[q];
  }
  float Ad[8];
#pragma unroll
  for (int j4 = 0; j4 < 8; j4 += 4) {
    float4 v = *(const float4*)&A_log[(size_t)d * NST + nb + j4];
    Ad[j4+0] = -__expf(v.x); Ad[j4+1] = -__expf(v.y);
    Ad[j4+2] = -__expf(v.z); Ad[j4+3] = -__expf(v.w);
  }
  const float w = dtw[d], b = dtb[d];
  float h[8], p[8];
#pragma unroll
  for (int n = 0; n < 8; ++n) { h[n] = 0.f; p[n] = 1.f; }
  __syncthreads();
#pragma unroll
  for (int t = 0; t < LC; ++t) {
    float dt  = softplus_f(fmaf(xps[t][32], w, b));
    float dtx = dt * xcf[t];
    f32x4 B0 = *(const f32x4*)&xps[t][nb];
    f32x4 B1 = *(const f32x4*)&xps[t][nb + 4];
    float Bv[8];
    *(f32x4*)&Bv[0] = B0; *(f32x4*)&Bv[4] = B1;
#pragma unroll
    for (int n = 0; n < 8; ++n) {
      float da = __expf(dt * Ad[n]);
      h[n] = fmaf(da, h[n], dtx * Bv[n]);
      p[n] *= da;
    }
  }
  size_t base = ((size_t)c * DI + d) * NST + nb;
  *(float4*)&P[base]     = make_float4(p[0], p[1], p[2], p[3]);
  *(float4*)&P[base + 4] = make_float4(p[4], p[5], p[6], p[7]);
  *(float4*)&Q[base]     = make_float4(h[0], h[1], h[2], h[3]);
  *(float4*)&Q[base + 4] = make_float4(h[4], h[5], h[6], h[7]);
}

// ---------------------------------------------------------------------------
// Scan phase B: sequential prefix over chunks, thread per (d, n4).
// QHs transformed IN PLACE: Q[c] (h_end local) -> Hs[c] (h_start global).
// ---------------------------------------------------------------------------
__global__ __launch_bounds__(256) void scan_prefix_k(
    const float* __restrict__ P, float* __restrict__ QHs) {
  const int g = blockIdx.x * 256 + threadIdx.x;   // 0..8191
  const int d = g >> 2;
  const int q = (g & 3) << 2;
  float4 h = make_float4(0.f, 0.f, 0.f, 0.f);
#pragma unroll 8
  for (int c = 0; c < NCHUNK; ++c) {
    size_t base = ((size_t)c * DI + d) * NST + q;
    float4 pv = *(const float4*)&P[base];
    float4 qv = *(const float4*)&QHs[base];
    *(float4*)&QHs[base] = h;
    h.x = fmaf(pv.x, h.x, qv.x);
    h.y = fmaf(pv.y, h.y, qv.y);
    h.z = fmaf(pv.z, h.z, qv.z);
    h.w = fmaf(pv.w, h.w, qv.w);
  }
}

// ---------------------------------------------------------------------------
// Scan phase C: seeded re-scan, n-split x2; y reduced via shfl_xor(1).
// xc + z prefetched to registers.  ys (bf16) = (scan_y + xc*D) * silu(z).
// ---------------------------------------------------------------------------
__global__ __launch_bounds__(256) void scan_final_k(
    const float* __restrict__ xcT, const float* __restrict__ xp,
    const float* __restrict__ dtw, const float* __restrict__ dtb,
    const float* __restrict__ A_log, const float* __restrict__ Dp,
    const float* __restrict__ Hs, const float* __restrict__ xz,
    ushort* __restrict__ ys) {
  const int tid  = threadIdx.x;
  const int d    = blockIdx.x * 128 + (tid >> 1);
  const int half = tid & 1;
  const int nb   = half * 8;
  const int c    = blockIdx.y;
  const int l0   = c * LC;
  __shared__ float xps[LC][36];
  stage_xps(xps, xp, l0, tid);

  float xcf[LC];
  {
    const float4* src = (const float4*)(xcT + (size_t)d * L_SEQ + l0);
#pragma unroll
    for (int q = 0; q < LC/4; ++q) *(float4*)&xcf[q*4] = src[q];
  }
  float zbuf[LC];
#pragma unroll
  for (int t = 0; t < LC; ++t)
    zbuf[t] = xz[(size_t)(l0 + t) * 4096 + 2048 + d];

  float Ad[8];
#pragma unroll
  for (int j4 = 0; j4 < 8; j4 += 4) {
    float4 v = *(const float4*)&A_log[(size_t)d * NST + nb + j4];
    Ad[j4+0] = -__expf(v.x); Ad[j4+1] = -__expf(v.y);
    Ad[j4+2] = -__expf(v.z); Ad[j4+3] = -__expf(v.w);
  }
  const float w = dtw[d], b = dtb[d], Dd = Dp[d];
  float h[8];
  size_t hb = ((size_t)c * DI + d) * NST + nb;
  *(float4*)&h[0] = *(const float4*)&Hs[hb];
  *(float4*)&h[4] = *(const float4*)&Hs[hb + 4];
  __syncthreads();
#pragma unroll
  for (int t = 0; t < LC; ++t) {
    const int l = l0 + t;
    float dt  = softplus_f(fmaf(xps[t][32], w, b));
    float dtx = dt * xcf[t];
    f32x4 B0 = *(const f32x4*)&xps[t][nb];
    f32x4 B1 = *(const f32x4*)&xps[t][nb + 4];
    f32x4 C0 = *(const f32x4*)&xps[t][16 + nb];
    f32x4 C1 = *(const f32x4*)&xps[t][20 + nb];
    float Bv[8], Cv[8];
    *(f32x4*)&Bv[0] = B0; *(f32x4*)&Bv[4] = B1;
    *(f32x4*)&Cv[0] = C0; *(f32x4*)&Cv[4] = C1;
    float y = 0.f;
#pragma unroll
    for (int n = 0; n < 8; ++n) {
      float da = __expf(dt * Ad[n]);
      h[n] = fmaf(da, h[n], dtx * Bv[n]);
      y = fmaf(h[n], Cv[n], y);
    }
    y += __shfl_xor(y, 1);
    if (half == 0) {
      y = fmaf(xcf[t], Dd, y);
      ys[(size_t)l * DI + d] = f2bf(y * silu_f(zbuf[t]));
    }
  }
}

// ---------------------------------------------------------------------------
extern "C" void kernel_launch(void* const* d_in, const int* in_sizes, int n_in,
                              void* d_out, int out_size, void* d_ws, size_t ws_size,
                              hipStream_t stream) {
  const float* x    = (const float*)d_in[0];   // (2048,1024)
  const float* W1   = (const float*)d_in[1];   // (4096,1024)
  const float* cw   = (const float*)d_in[2];   // (2048,1,4)
  const float* cb   = (const float*)d_in[3];   // (2048,)
  const float* Wxp  = (const float*)d_in[4];   // (33,2048)
  const float* dtw  = (const float*)d_in[5];   // (2048,1)
  const float* dtb  = (const float*)d_in[6];   // (2048,)
  const float* Alog = (const float*)d_in[7];   // (2048,16)
  const float* Dp   = (const float*)d_in[8];   // (2048,)
  const float* Wout = (const float*)d_in[9];   // (1024,2048)
  float* out = (float*)d_out;                  // (2048,1024)

  char* w = (char*)d_ws;
  float*  xz      = (float*)w;                    // [0, 33554432)
  float*  xcT     = (float*)(w + 33554432);       // [33554432, 50331648)  (d, l)
  // --- region [50331648, 67108864): xc row-major; aliased before by
  //     x_bf/W1_bf (dead after GEMM1), after gemm_xp by P/QHs ---
  float*  xc_rm   = (float*)(w + 50331648);       // 16,777,216 B
  ushort* x_bf    = (ushort*)(w + 50331648);      //  4 MiB
  ushort* W1_bf   = (ushort*)(w + 54525952);      //  8 MiB
  float*  P       = (float*)(w + 50331648);       //  8,388,608 B
  float*  QHs     = (float*)(w + 58720256);       //  8,388,608 B
  // --- persistent tail ---
  float*  xp      = (float*)(w + 67108864);       //    294,912 B
  ushort* Wout_bf = (ushort*)(w + 67403776);      //  4 MiB
  ushort* ys_bf   = (ushort*)(w + 71598080);      //  8 MiB (aliased early by xp_part)
  float*  xp_part = (float*)(w + 71598080);       //  2,359,296 B, dead before scan_final
  // total = 79,986,688 B

  // 0. fp32 -> bf16 conversions
  cvt_bf16_k<<<2048, 256, 0, stream>>>(x,    x_bf,    2048*1024/4);
  cvt_bf16_k<<<4096, 256, 0, stream>>>(W1,   W1_bf,   4096*1024/4);
  cvt_bf16_k<<<2048, 256, 0, stream>>>(Wout, Wout_bf, 1024*2048/4);
  // 1. xz = x @ in_proj_w^T   (MFMA bf16)
  gemm_mfma_bf16<4><<<dim3(4096/128, 2048/128), 256, 0, stream>>>(x_bf, W1_bf, xz, DM, 4096);
  // 2. depthwise conv + silu  (writes xc row-major; x_bf/W1_bf now dead)
  conv_silu_k<<<dim3(DI/256, L_SEQ), 256, 0, stream>>>(xz, cw, cb, xc_rm);
  // 2b. transpose to (d, l) for the scan
  transpose_k<<<dim3(DI/64, L_SEQ/64), 256, 0, stream>>>(xc_rm, xcT);
  // 3. xp = xc @ x_proj_w^T  (split-K partials + reduce)
  gemm_xp_k<<<dim3(L_SEQ/64, KSPLIT), 256, 0, stream>>>(xc_rm, Wxp, xp_part);
  reduce_xp_k<<<L_SEQ*XP_LD/256, 256, 0, stream>>>(xp_part, xp);
  // 4. chunked selective scan (xc_rm dead; P/QHs reuse its region)
  scan_partial_k<<<dim3(DI/128, NCHUNK), 256, 0, stream>>>(xcT, xp, dtw, dtb, Alog, P, QHs);
  scan_prefix_k<<<DI*NST/4/256, 256, 0, stream>>>(P, QHs);
  scan_final_k<<<dim3(DI/128, NCHUNK), 256, 0, stream>>>(xcT, xp, dtw, dtb, Alog, Dp, QHs, xz, ys_bf);
  // 5. out = ys @ out_proj_w^T   (MFMA bf16, BM=64 for 256-block grid)
  gemm_mfma_bf16<2><<<dim3(1024/128, 2048/64), 256, 0, stream>>>(ys_bf, Wout_bf, out, DI, 1024);
}

// Round 8
// 335.781 us; speedup vs baseline: 1.2797x; 1.2797x over previous
//
#include <hip/hip_runtime.h>
#include <math.h>

#define L_SEQ   2048
#define DM      1024
#define DI      2048
#define NST     16
#define LC      32      // chunk length for scan
#define NCHUNK  64      // L_SEQ / LC
#define XP_LD   36      // padded leading dim for xp (33 cols)
#define KSPLIT  8       // K-splits for gemm_xp

typedef short s16x8 __attribute__((ext_vector_type(8)));
typedef float f32x4 __attribute__((ext_vector_type(4)));

__device__ __forceinline__ float silu_f(float x) {
  return x / (1.0f + __expf(-x));
}
__device__ __forceinline__ float softplus_f(float x) {
  return x > 20.0f ? x : log1pf(__expf(x));
}
// fp32 -> bf16 RNE
__device__ __forceinline__ ushort f2bf(float f) {
  unsigned int u = __float_as_uint(f);
  unsigned int r = (u + 0x7fffu + ((u >> 16) & 1u)) >> 16;
  return (ushort)r;
}
__device__ __forceinline__ void gload_lds16(const void* g, void* lds) {
  __builtin_amdgcn_global_load_lds(
      (const __attribute__((address_space(1))) unsigned int*)g,
      (__attribute__((address_space(3))) unsigned int*)lds,
      16, 0, 0);
}

// ---------------------------------------------------------------------------
// fp32 -> bf16 conversion, 4 elems/thread
// ---------------------------------------------------------------------------
__global__ __launch_bounds__(256) void cvt_bf16_k(
    const float* __restrict__ in, ushort* __restrict__ out, int n4) {
  int i = blockIdx.x * 256 + threadIdx.x;
  if (i >= n4) return;
  float4 v = ((const float4*)in)[i];
  ushort4 o;
  o.x = f2bf(v.x); o.y = f2bf(v.y); o.z = f2bf(v.z); o.w = f2bf(v.w);
  ((ushort4*)out)[i] = o;
}

// ---------------------------------------------------------------------------
// bf16 MFMA GEMM: C(MxN fp32) = A(MxK bf16,row-major) * B(NxK bf16,row-major)^T
// m97 structure: BK=32, 256 thr = 4 waves (2x2), wave tile = MFRAG*16 x 64.
// BM = MFRAG*32, BN = 128.  grid = (N/128, M/BM).
// ---------------------------------------------------------------------------
template <int MFRAG>
__global__ __launch_bounds__(256) void gemm_mfma_bf16(
    const ushort* __restrict__ A, const ushort* __restrict__ B,
    float* __restrict__ C, int K, int ldc) {
  constexpr int BM = MFRAG * 32;
  __shared__ ushort As[BM * 32];
  __shared__ ushort Bs[128 * 32];
  const int tid  = threadIdx.x;
  const int lane = tid & 63;
  const int wv   = tid >> 6;
  const int wr   = wv >> 1;   // wave row 0..1
  const int wc   = wv & 1;    // wave col 0..1
  const int m0 = blockIdx.y * BM;
  const int n0 = blockIdx.x * 128;

  f32x4 acc[MFRAG][4] = {};

  const int kc = (tid & 3) * 8;   // bf16-element offset of this thread's 16B chunk

  for (int k0 = 0; k0 < K; k0 += 32) {
    __syncthreads();
    // stage A tile: BM rows x 32 cols bf16 = BM*4 chunks of 16B
#pragma unroll
    for (int q = 0; q < BM / 64; ++q) {
      int id = q * 256 + tid;
      int m  = id >> 2;
      gload_lds16(A + (size_t)(m0 + m) * K + k0 + kc, (char*)As + id * 16);
    }
    // stage B tile: 128 rows x 32 cols
#pragma unroll
    for (int q = 0; q < 2; ++q) {
      int id = q * 256 + tid;
      int n  = id >> 2;
      gload_lds16(B + (size_t)(n0 + n) * K + k0 + kc, (char*)Bs + id * 16);
    }
    __syncthreads();   // drains vmcnt before reads

    s16x8 af[MFRAG], bfr[4];
#pragma unroll
    for (int m = 0; m < MFRAG; ++m)
      af[m] = *(const s16x8*)&As[(wr * MFRAG * 16 + m * 16 + (lane & 15)) * 32 + (lane >> 4) * 8];
#pragma unroll
    for (int n = 0; n < 4; ++n)
      bfr[n] = *(const s16x8*)&Bs[(wc * 64 + n * 16 + (lane & 15)) * 32 + (lane >> 4) * 8];
#pragma unroll
    for (int m = 0; m < MFRAG; ++m)
#pragma unroll
      for (int n = 0; n < 4; ++n)
        acc[m][n] = __builtin_amdgcn_mfma_f32_16x16x32_bf16(af[m], bfr[n], acc[m][n], 0, 0, 0);
  }
  // epilogue: C/D layout col=lane&15, row=(lane>>4)*4+reg  [m89-verified]
  const int cr = (lane >> 4) * 4;
  const int cc = lane & 15;
#pragma unroll
  for (int m = 0; m < MFRAG; ++m) {
    int gr0 = m0 + wr * MFRAG * 16 + m * 16 + cr;
#pragma unroll
    for (int n = 0; n < 4; ++n) {
      int gc = n0 + wc * 64 + n * 16 + cc;
#pragma unroll
      for (int r = 0; r < 4; ++r)
        C[(size_t)(gr0 + r) * ldc + gc] = acc[m][n][r];
    }
  }
}

// ---------------------------------------------------------------------------
// Depthwise causal conv (D_CONV=4) + bias + silu.  Writes xc (l,d) row-major.
// ---------------------------------------------------------------------------
__global__ __launch_bounds__(256) void conv_silu_k(
    const float* __restrict__ xz, const float* __restrict__ cw,
    const float* __restrict__ cb, float* __restrict__ xc) {
  const int d = blockIdx.x * 256 + threadIdx.x;
  const int l = blockIdx.y;
  const float w0 = cw[d*4+0], w1 = cw[d*4+1], w2 = cw[d*4+2], w3 = cw[d*4+3];
  float acc = cb[d];
  if (l >= 3) acc = fmaf(w0, xz[(size_t)(l-3)*4096 + d], acc);
  if (l >= 2) acc = fmaf(w1, xz[(size_t)(l-2)*4096 + d], acc);
  if (l >= 1) acc = fmaf(w2, xz[(size_t)(l-1)*4096 + d], acc);
  acc = fmaf(w3, xz[(size_t)l*4096 + d], acc);
  xc[(size_t)l*DI + d] = silu_f(acc);
}

// ---------------------------------------------------------------------------
// 64x64 LDS-tiled transpose: xcT[d][l] = xc[l][d].  grid (DI/64, L/64).
// ---------------------------------------------------------------------------
__global__ __launch_bounds__(256) void transpose_k(
    const float* __restrict__ in, float* __restrict__ out) {
  __shared__ float tile[64][65];
  const int d0 = blockIdx.x * 64, l0 = blockIdx.y * 64;
  const int r  = threadIdx.x >> 4;
  const int c4 = (threadIdx.x & 15) * 4;
#pragma unroll
  for (int p = 0; p < 4; ++p) {
    float4 v = *(const float4*)&in[(size_t)(l0 + r + p*16) * DI + d0 + c4];
    tile[r + p*16][c4+0] = v.x; tile[r + p*16][c4+1] = v.y;
    tile[r + p*16][c4+2] = v.z; tile[r + p*16][c4+3] = v.w;
  }
  __syncthreads();
  const int dd = threadIdx.x >> 4;
  const int l4 = (threadIdx.x & 15) * 4;
#pragma unroll
  for (int p = 0; p < 4; ++p) {
    float4 v;
    v.x = tile[l4+0][dd + p*16];
    v.y = tile[l4+1][dd + p*16];
    v.z = tile[l4+2][dd + p*16];
    v.w = tile[l4+3][dd + p*16];
    *(float4*)&out[(size_t)(d0 + dd + p*16) * L_SEQ + l0 + l4] = v;
  }
}

// ---------------------------------------------------------------------------
// xp partials: split-K over KSPLIT slices of 256.
// grid = (L/64, KSPLIT).  Per block: 64 rows x 33 cols, K-slice 256.
// ---------------------------------------------------------------------------
__global__ __launch_bounds__(256) void gemm_xp_k(
    const float* __restrict__ xc, const float* __restrict__ Wxp,
    float* __restrict__ xp_part) {
  const int L0   = blockIdx.x * 64;
  const int ks   = blockIdx.y;
  const int wv   = threadIdx.x >> 6;
  const int lane = threadIdx.x & 63;
  __shared__ float xcs[64][65];
  __shared__ float Ws[36][64];
  float acc[9] = {};
  const int kbeg = ks * (DI / KSPLIT);
  const int kend = kbeg + DI / KSPLIT;
  for (int k0 = kbeg; k0 < kend; k0 += 64) {
    {
      int r = threadIdx.x >> 2;
      int cbase = (threadIdx.x & 3) * 16;
#pragma unroll
      for (int q = 0; q < 4; ++q) {
        float4 v = *(const float4*)&xc[(size_t)(L0 + r) * DI + k0 + cbase + q*4];
        xcs[r][cbase + q*4 + 0] = v.x; xcs[r][cbase + q*4 + 1] = v.y;
        xcs[r][cbase + q*4 + 2] = v.z; xcs[r][cbase + q*4 + 3] = v.w;
      }
    }
    for (int idx = threadIdx.x; idx < 36 * 16; idx += 256) {
      int j = idx >> 4; int cc = (idx & 15) << 2;
      float4 v = make_float4(0.f, 0.f, 0.f, 0.f);
      if (j < 33) v = *(const float4*)&Wxp[(size_t)j * DI + k0 + cc];
      *(float4*)&Ws[j][cc] = v;
    }
    __syncthreads();
#pragma unroll 4
    for (int kk = 0; kk < 64; kk += 4) {
      float4 wr[9];
#pragma unroll
      for (int jj = 0; jj < 9; ++jj) wr[jj] = *(const float4*)&Ws[wv*9 + jj][kk];
      float a0 = xcs[lane][kk+0], a1 = xcs[lane][kk+1];
      float a2 = xcs[lane][kk+2], a3 = xcs[lane][kk+3];
#pragma unroll
      for (int jj = 0; jj < 9; ++jj) {
        acc[jj] = fmaf(a0, wr[jj].x, acc[jj]);
        acc[jj] = fmaf(a1, wr[jj].y, acc[jj]);
        acc[jj] = fmaf(a2, wr[jj].z, acc[jj]);
        acc[jj] = fmaf(a3, wr[jj].w, acc[jj]);
      }
    }
    __syncthreads();
  }
  const int l = L0 + lane;
#pragma unroll
  for (int jj = 0; jj < 9; ++jj) {
    int j = wv * 9 + jj;
    if (j < 33)
      xp_part[(size_t)ks * L_SEQ * XP_LD + (size_t)l * XP_LD + j] = acc[jj];
  }
}

// ---------------------------------------------------------------------------
// Reduce split-K partials: xp = sum_ks xp_part[ks].
// ---------------------------------------------------------------------------
__global__ __launch_bounds__(256) void reduce_xp_k(
    const float* __restrict__ part, float* __restrict__ xp) {
  int i = blockIdx.x * 256 + threadIdx.x;
  float s = 0.f;
#pragma unroll
  for (int ks = 0; ks < KSPLIT; ++ks)
    s += part[(size_t)ks * L_SEQ * XP_LD + i];
  xp[i] = s;
}

// ---------------------------------------------------------------------------
// LDS staging for scan: xps row = [B 0..15 | C 16..31 | dtr 32], stride 36.
// ---------------------------------------------------------------------------
__device__ __forceinline__ void stage_xps(
    float (*xps)[36], const float* __restrict__ xp, int l0, int tid) {
  for (int idx = tid; idx < LC * 33; idx += 256) {
    int rr = idx / 33, j = idx - rr * 33;
    int col = (j == 0) ? 32 : j - 1;
    xps[rr][col] = xp[(size_t)(l0 + rr) * XP_LD + j];
  }
}

// ---------------------------------------------------------------------------
// Coalesced xcT chunk staging: xcs[128 d][LC t] (pad 33).
// Lanes 0..7 cover one 128B d-row -> full cache lines; LDS write 2-way (free).
// Per-t read xcs[dl][t]: banks (dl+t)%32 -> conflict-free, pair-broadcast.
// ---------------------------------------------------------------------------
__device__ __forceinline__ void stage_xcs(
    float (*xcs)[LC + 1], const float* __restrict__ xcT, int d0, int l0, int tid) {
#pragma unroll
  for (int q = 0; q < 4; ++q) {
    int f4  = q * 256 + tid;            // 0..1023
    int row = f4 >> 3;                  // 0..127
    int col = (f4 & 7) * 4;             // 0..28
    float4 v = *(const float4*)&xcT[(size_t)(d0 + row) * L_SEQ + l0 + col];
    xcs[row][col+0] = v.x; xcs[row][col+1] = v.y;
    xcs[row][col+2] = v.z; xcs[row][col+3] = v.w;
  }
}

// ---------------------------------------------------------------------------
// Scan phase A: per-chunk local scan from h=0, n-split x2 (8 states/thread).
// All t-loop operands come from LDS.  grid = (DI/128, NCHUNK), 256 thr.
// ---------------------------------------------------------------------------
__global__ __launch_bounds__(256) void scan_partial_k(
    const float* __restrict__ xcT, const float* __restrict__ xp,
    const float* __restrict__ dtw, const float* __restrict__ dtb,
    const float* __restrict__ A_log,
    float* __restrict__ P, float* __restrict__ Q) {
  const int tid = threadIdx.x;
  const int dl  = tid >> 1;
  const int d0  = blockIdx.x * 128;
  const int d   = d0 + dl;
  const int nb  = (tid & 1) * 8;
  const int c   = blockIdx.y;
  const int l0  = c * LC;
  __shared__ float xps[LC][36];
  __shared__ float xcs[128][LC + 1];
  stage_xps(xps, xp, l0, tid);
  stage_xcs(xcs, xcT, d0, l0, tid);

  float Ad[8];
#pragma unroll
  for (int j4 = 0; j4 < 8; j4 += 4) {
    float4 v = *(const float4*)&A_log[(size_t)d * NST + nb + j4];
    Ad[j4+0] = -__expf(v.x); Ad[j4+1] = -__expf(v.y);
    Ad[j4+2] = -__expf(v.z); Ad[j4+3] = -__expf(v.w);
  }
  const float w = dtw[d], b = dtb[d];
  float h[8], p[8];
#pragma unroll
  for (int n = 0; n < 8; ++n) { h[n] = 0.f; p[n] = 1.f; }
  __syncthreads();
#pragma unroll
  for (int t = 0; t < LC; ++t) {
    float dt  = softplus_f(fmaf(xps[t][32], w, b));
    float dtx = dt * xcs[dl][t];
    f32x4 B0 = *(const f32x4*)&xps[t][nb];
    f32x4 B1 = *(const f32x4*)&xps[t][nb + 4];
    float Bv[8];
    *(f32x4*)&Bv[0] = B0; *(f32x4*)&Bv[4] = B1;
#pragma unroll
    for (int n = 0; n < 8; ++n) {
      float da = __expf(dt * Ad[n]);
      h[n] = fmaf(da, h[n], dtx * Bv[n]);
      p[n] *= da;
    }
  }
  size_t base = ((size_t)c * DI + d) * NST + nb;
  *(float4*)&P[base]     = make_float4(p[0], p[1], p[2], p[3]);
  *(float4*)&P[base + 4] = make_float4(p[4], p[5], p[6], p[7]);
  *(float4*)&Q[base]     = make_float4(h[0], h[1], h[2], h[3]);
  *(float4*)&Q[base + 4] = make_float4(h[4], h[5], h[6], h[7]);
}

// ---------------------------------------------------------------------------
// Scan phase B: sequential prefix over chunks, thread per (d, n4).
// QHs transformed IN PLACE: Q[c] (h_end local) -> Hs[c] (h_start global).
// ---------------------------------------------------------------------------
__global__ __launch_bounds__(256) void scan_prefix_k(
    const float* __restrict__ P, float* __restrict__ QHs) {
  const int g = blockIdx.x * 256 + threadIdx.x;   // 0..8191
  const int d = g >> 2;
  const int q = (g & 3) << 2;
  float4 h = make_float4(0.f, 0.f, 0.f, 0.f);
#pragma unroll 8
  for (int c = 0; c < NCHUNK; ++c) {
    size_t base = ((size_t)c * DI + d) * NST + q;
    float4 pv = *(const float4*)&P[base];
    float4 qv = *(const float4*)&QHs[base];
    *(float4*)&QHs[base] = h;
    h.x = fmaf(pv.x, h.x, qv.x);
    h.y = fmaf(pv.y, h.y, qv.y);
    h.z = fmaf(pv.z, h.z, qv.z);
    h.w = fmaf(pv.w, h.w, qv.w);
  }
}

// ---------------------------------------------------------------------------
// Scan phase C: seeded re-scan, n-split x2; y reduced via shfl_xor(1).
// xc chunk + z slice staged in LDS (z via global_load_lds, linear layout).
// ys (bf16) = (scan_y + xc*D) * silu(z).  grid = (DI/128, NCHUNK).
// ---------------------------------------------------------------------------
__global__ __launch_bounds__(256) void scan_final_k(
    const float* __restrict__ xcT, const float* __restrict__ xp,
    const float* __restrict__ dtw, const float* __restrict__ dtb,
    const float* __restrict__ A_log, const float* __restrict__ Dp,
    const float* __restrict__ Hs, const float* __restrict__ xz,
    ushort* __restrict__ ys) {
  const int tid  = threadIdx.x;
  const int dl   = tid >> 1;
  const int d0   = blockIdx.x * 128;
  const int d    = d0 + dl;
  const int half = tid & 1;
  const int nb   = half * 8;
  const int c    = blockIdx.y;
  const int l0   = c * LC;
  __shared__ float xps[LC][36];
  __shared__ float xcs[128][LC + 1];
  __shared__ float zs[LC][128];     // [t][d], linear for global_load_lds
  // z slice: id = t*32 + c4  ->  lds off id*16  (lane-contiguous, linear)
#pragma unroll
  for (int q = 0; q < 4; ++q) {
    int id = q * 256 + tid;
    int t  = id >> 5;
    int c4 = (id & 31) * 4;
    gload_lds16(xz + (size_t)(l0 + t) * 4096 + 2048 + d0 + c4,
                (char*)zs + id * 16);
  }
  stage_xps(xps, xp, l0, tid);
  stage_xcs(xcs, xcT, d0, l0, tid);

  float Ad[8];
#pragma unroll
  for (int j4 = 0; j4 < 8; j4 += 4) {
    float4 v = *(const float4*)&A_log[(size_t)d * NST + nb + j4];
    Ad[j4+0] = -__expf(v.x); Ad[j4+1] = -__expf(v.y);
    Ad[j4+2] = -__expf(v.z); Ad[j4+3] = -__expf(v.w);
  }
  const float w = dtw[d], b = dtb[d], Dd = Dp[d];
  float h[8];
  size_t hb = ((size_t)c * DI + d) * NST + nb;
  *(float4*)&h[0] = *(const float4*)&Hs[hb];
  *(float4*)&h[4] = *(const float4*)&Hs[hb + 4];
  __syncthreads();    // also drains the global_load_lds (vmcnt) per G-contract
#pragma unroll
  for (int t = 0; t < LC; ++t) {
    const int l = l0 + t;
    float dt  = softplus_f(fmaf(xps[t][32], w, b));
    float xcv = xcs[dl][t];
    float dtx = dt * xcv;
    f32x4 B0 = *(const f32x4*)&xps[t][nb];
    f32x4 B1 = *(const f32x4*)&xps[t][nb + 4];
    f32x4 C0 = *(const f32x4*)&xps[t][16 + nb];
    f32x4 C1 = *(const f32x4*)&xps[t][20 + nb];
    float Bv[8], Cv[8];
    *(f32x4*)&Bv[0] = B0; *(f32x4*)&Bv[4] = B1;
    *(f32x4*)&Cv[0] = C0; *(f32x4*)&Cv[4] = C1;
    float y = 0.f;
#pragma unroll
    for (int n = 0; n < 8; ++n) {
      float da = __expf(dt * Ad[n]);
      h[n] = fmaf(da, h[n], dtx * Bv[n]);
      y = fmaf(h[n], Cv[n], y);
    }
    y += __shfl_xor(y, 1);
    if (half == 0) {
      y = fmaf(xcv, Dd, y);
      ys[(size_t)l * DI + d] = f2bf(y * silu_f(zs[t][dl]));
    }
  }
}

// ---------------------------------------------------------------------------
extern "C" void kernel_launch(void* const* d_in, const int* in_sizes, int n_in,
                              void* d_out, int out_size, void* d_ws, size_t ws_size,
                              hipStream_t stream) {
  const float* x    = (const float*)d_in[0];   // (2048,1024)
  const float* W1   = (const float*)d_in[1];   // (4096,1024)
  const float* cw   = (const float*)d_in[2];   // (2048,1,4)
  const float* cb   = (const float*)d_in[3];   // (2048,)
  const float* Wxp  = (const float*)d_in[4];   // (33,2048)
  const float* dtw  = (const float*)d_in[5];   // (2048,1)
  const float* dtb  = (const float*)d_in[6];   // (2048,)
  const float* Alog = (const float*)d_in[7];   // (2048,16)
  const float* Dp   = (const float*)d_in[8];   // (2048,)
  const float* Wout = (const float*)d_in[9];   // (1024,2048)
  float* out = (float*)d_out;                  // (2048,1024)

  char* w = (char*)d_ws;
  float*  xz      = (float*)w;                    // [0, 33554432)
  float*  xcT     = (float*)(w + 33554432);       // [33554432, 50331648)  (d, l)
  // --- region [50331648, 67108864): xc row-major; aliased before by
  //     x_bf/W1_bf (dead after GEMM1), after gemm_xp by P/QHs ---
  float*  xc_rm   = (float*)(w + 50331648);       // 16,777,216 B
  ushort* x_bf    = (ushort*)(w + 50331648);      //  4 MiB
  ushort* W1_bf   = (ushort*)(w + 54525952);      //  8 MiB
  float*  P       = (float*)(w + 50331648);       //  8,388,608 B
  float*  QHs     = (float*)(w + 58720256);       //  8,388,608 B
  // --- persistent tail ---
  float*  xp      = (float*)(w + 67108864);       //    294,912 B
  ushort* Wout_bf = (ushort*)(w + 67403776);      //  4 MiB
  ushort* ys_bf   = (ushort*)(w + 71598080);      //  8 MiB (aliased early by xp_part)
  float*  xp_part = (float*)(w + 71598080);       //  2,359,296 B, dead before scan_final
  // total = 79,986,688 B

  // 0. fp32 -> bf16 conversions
  cvt_bf16_k<<<2048, 256, 0, stream>>>(x,    x_bf,    2048*1024/4);
  cvt_bf16_k<<<4096, 256, 0, stream>>>(W1,   W1_bf,   4096*1024/4);
  cvt_bf16_k<<<2048, 256, 0, stream>>>(Wout, Wout_bf, 1024*2048/4);
  // 1. xz = x @ in_proj_w^T   (MFMA bf16)
  gemm_mfma_bf16<4><<<dim3(4096/128, 2048/128), 256, 0, stream>>>(x_bf, W1_bf, xz, DM, 4096);
  // 2. depthwise conv + silu  (writes xc row-major; x_bf/W1_bf now dead)
  conv_silu_k<<<dim3(DI/256, L_SEQ), 256, 0, stream>>>(xz, cw, cb, xc_rm);
  // 2b. transpose to (d, l) for the scan
  transpose_k<<<dim3(DI/64, L_SEQ/64), 256, 0, stream>>>(xc_rm, xcT);
  // 3. xp = xc @ x_proj_w^T  (split-K partials + reduce)
  gemm_xp_k<<<dim3(L_SEQ/64, KSPLIT), 256, 0, stream>>>(xc_rm, Wxp, xp_part);
  reduce_xp_k<<<L_SEQ*XP_LD/256, 256, 0, stream>>>(xp_part, xp);
  // 4. chunked selective scan (xc_rm dead; P/QHs reuse its region)
  scan_partial_k<<<dim3(DI/128, NCHUNK), 256, 0, stream>>>(xcT, xp, dtw, dtb, Alog, P, QHs);
  scan_prefix_k<<<DI*NST/4/256, 256, 0, stream>>>(P, QHs);
  scan_final_k<<<dim3(DI/128, NCHUNK), 256, 0, stream>>>(xcT, xp, dtw, dtb, Alog, Dp, QHs, xz, ys_bf);
  // 5. out = ys @ out_proj_w^T   (MFMA bf16, BM=64 for 256-block grid)
  gemm_mfma_bf16<2><<<dim3(1024/128, 2048/64), 256, 0, stream>>>(ys_bf, Wout_bf, out, DI, 1024);
}

// Round 9
// 278.800 us; speedup vs baseline: 1.5412x; 1.2044x over previous
//
#include <hip/hip_runtime.h>
#include <math.h>

#define L_SEQ   2048
#define DM      1024
#define DI      2048
#define NST     16
#define LC      32      // chunk length for scan
#define NCHUNK  64      // L_SEQ / LC
#define XP_LD   36      // padded leading dim for xp (33 cols)
#define KSPLIT  8       // K-splits for gemm_xp
#define LOG2E   1.44269504f

typedef short s16x8 __attribute__((ext_vector_type(8)));
typedef float f32x4 __attribute__((ext_vector_type(4)));

__device__ __forceinline__ float silu_f(float x) {
  return x / (1.0f + __expf(-x));
}
// fast softplus: log1p(exp x) == log(1+exp x); fast log is safe here
// (arg in [1, 5e8]; worst-case abs err ~1e-7·|result|, threshold 0.155)
__device__ __forceinline__ float softplus_f(float x) {
  return x > 20.0f ? x : __logf(1.0f + __expf(x));
}
// fp32 -> bf16 RNE
__device__ __forceinline__ ushort f2bf(float f) {
  unsigned int u = __float_as_uint(f);
  unsigned int r = (u + 0x7fffu + ((u >> 16) & 1u)) >> 16;
  return (ushort)r;
}
__device__ __forceinline__ void gload_lds16(const void* g, void* lds) {
  __builtin_amdgcn_global_load_lds(
      (const __attribute__((address_space(1))) unsigned int*)g,
      (__attribute__((address_space(3))) unsigned int*)lds,
      16, 0, 0);
}

// ---------------------------------------------------------------------------
// fp32 -> bf16 conversion, 4 elems/thread
// ---------------------------------------------------------------------------
__global__ __launch_bounds__(256) void cvt_bf16_k(
    const float* __restrict__ in, ushort* __restrict__ out, int n4) {
  int i = blockIdx.x * 256 + threadIdx.x;
  if (i >= n4) return;
  float4 v = ((const float4*)in)[i];
  ushort4 o;
  o.x = f2bf(v.x); o.y = f2bf(v.y); o.z = f2bf(v.z); o.w = f2bf(v.w);
  ((ushort4*)out)[i] = o;
}

// ---------------------------------------------------------------------------
// bf16 MFMA GEMM: C(MxN fp32) = A(MxK bf16,row-major) * B(NxK bf16,row-major)^T
// m97 structure: BK=32, 256 thr = 4 waves (2x2), wave tile = MFRAG*16 x 64.
// BM = MFRAG*32, BN = 128.  grid = (N/128, M/BM).
// ---------------------------------------------------------------------------
template <int MFRAG>
__global__ __launch_bounds__(256) void gemm_mfma_bf16(
    const ushort* __restrict__ A, const ushort* __restrict__ B,
    float* __restrict__ C, int K, int ldc) {
  constexpr int BM = MFRAG * 32;
  __shared__ ushort As[BM * 32];
  __shared__ ushort Bs[128 * 32];
  const int tid  = threadIdx.x;
  const int lane = tid & 63;
  const int wv   = tid >> 6;
  const int wr   = wv >> 1;   // wave row 0..1
  const int wc   = wv & 1;    // wave col 0..1
  const int m0 = blockIdx.y * BM;
  const int n0 = blockIdx.x * 128;

  f32x4 acc[MFRAG][4] = {};

  const int kc = (tid & 3) * 8;   // bf16-element offset of this thread's 16B chunk

  for (int k0 = 0; k0 < K; k0 += 32) {
    __syncthreads();
    // stage A tile: BM rows x 32 cols bf16 = BM*4 chunks of 16B
#pragma unroll
    for (int q = 0; q < BM / 64; ++q) {
      int id = q * 256 + tid;
      int m  = id >> 2;
      gload_lds16(A + (size_t)(m0 + m) * K + k0 + kc, (char*)As + id * 16);
    }
    // stage B tile: 128 rows x 32 cols
#pragma unroll
    for (int q = 0; q < 2; ++q) {
      int id = q * 256 + tid;
      int n  = id >> 2;
      gload_lds16(B + (size_t)(n0 + n) * K + k0 + kc, (char*)Bs + id * 16);
    }
    __syncthreads();   // drains vmcnt before reads

    s16x8 af[MFRAG], bfr[4];
#pragma unroll
    for (int m = 0; m < MFRAG; ++m)
      af[m] = *(const s16x8*)&As[(wr * MFRAG * 16 + m * 16 + (lane & 15)) * 32 + (lane >> 4) * 8];
#pragma unroll
    for (int n = 0; n < 4; ++n)
      bfr[n] = *(const s16x8*)&Bs[(wc * 64 + n * 16 + (lane & 15)) * 32 + (lane >> 4) * 8];
#pragma unroll
    for (int m = 0; m < MFRAG; ++m)
#pragma unroll
      for (int n = 0; n < 4; ++n)
        acc[m][n] = __builtin_amdgcn_mfma_f32_16x16x32_bf16(af[m], bfr[n], acc[m][n], 0, 0, 0);
  }
  // epilogue: C/D layout col=lane&15, row=(lane>>4)*4+reg  [m89-verified]
  const int cr = (lane >> 4) * 4;
  const int cc = lane & 15;
#pragma unroll
  for (int m = 0; m < MFRAG; ++m) {
    int gr0 = m0 + wr * MFRAG * 16 + m * 16 + cr;
#pragma unroll
    for (int n = 0; n < 4; ++n) {
      int gc = n0 + wc * 64 + n * 16 + cc;
#pragma unroll
      for (int r = 0; r < 4; ++r)
        C[(size_t)(gr0 + r) * ldc + gc] = acc[m][n][r];
    }
  }
}

// ---------------------------------------------------------------------------
// Depthwise causal conv (D_CONV=4) + bias + silu.  Writes xc (l,d) row-major.
// ---------------------------------------------------------------------------
__global__ __launch_bounds__(256) void conv_silu_k(
    const float* __restrict__ xz, const float* __restrict__ cw,
    const float* __restrict__ cb, float* __restrict__ xc) {
  const int d = blockIdx.x * 256 + threadIdx.x;
  const int l = blockIdx.y;
  const float w0 = cw[d*4+0], w1 = cw[d*4+1], w2 = cw[d*4+2], w3 = cw[d*4+3];
  float acc = cb[d];
  if (l >= 3) acc = fmaf(w0, xz[(size_t)(l-3)*4096 + d], acc);
  if (l >= 2) acc = fmaf(w1, xz[(size_t)(l-2)*4096 + d], acc);
  if (l >= 1) acc = fmaf(w2, xz[(size_t)(l-1)*4096 + d], acc);
  acc = fmaf(w3, xz[(size_t)l*4096 + d], acc);
  xc[(size_t)l*DI + d] = silu_f(acc);
}

// ---------------------------------------------------------------------------
// 64x64 LDS-tiled transpose: xcT[d][l] = xc[l][d].  grid (DI/64, L/64).
// ---------------------------------------------------------------------------
__global__ __launch_bounds__(256) void transpose_k(
    const float* __restrict__ in, float* __restrict__ out) {
  __shared__ float tile[64][65];
  const int d0 = blockIdx.x * 64, l0 = blockIdx.y * 64;
  const int r  = threadIdx.x >> 4;
  const int c4 = (threadIdx.x & 15) * 4;
#pragma unroll
  for (int p = 0; p < 4; ++p) {
    float4 v = *(const float4*)&in[(size_t)(l0 + r + p*16) * DI + d0 + c4];
    tile[r + p*16][c4+0] = v.x; tile[r + p*16][c4+1] = v.y;
    tile[r + p*16][c4+2] = v.z; tile[r + p*16][c4+3] = v.w;
  }
  __syncthreads();
  const int dd = threadIdx.x >> 4;
  const int l4 = (threadIdx.x & 15) * 4;
#pragma unroll
  for (int p = 0; p < 4; ++p) {
    float4 v;
    v.x = tile[l4+0][dd + p*16];
    v.y = tile[l4+1][dd + p*16];
    v.z = tile[l4+2][dd + p*16];
    v.w = tile[l4+3][dd + p*16];
    *(float4*)&out[(size_t)(d0 + dd + p*16) * L_SEQ + l0 + l4] = v;
  }
}

// ---------------------------------------------------------------------------
// xp partials: split-K over KSPLIT slices of 256.
// grid = (L/64, KSPLIT).  Per block: 64 rows x 33 cols, K-slice 256.
// ---------------------------------------------------------------------------
__global__ __launch_bounds__(256) void gemm_xp_k(
    const float* __restrict__ xc, const float* __restrict__ Wxp,
    float* __restrict__ xp_part) {
  const int L0   = blockIdx.x * 64;
  const int ks   = blockIdx.y;
  const int wv   = threadIdx.x >> 6;
  const int lane = threadIdx.x & 63;
  __shared__ float xcs[64][65];
  __shared__ float Ws[36][64];
  float acc[9] = {};
  const int kbeg = ks * (DI / KSPLIT);
  const int kend = kbeg + DI / KSPLIT;
  for (int k0 = kbeg; k0 < kend; k0 += 64) {
    {
      int r = threadIdx.x >> 2;
      int cbase = (threadIdx.x & 3) * 16;
#pragma unroll
      for (int q = 0; q < 4; ++q) {
        float4 v = *(const float4*)&xc[(size_t)(L0 + r) * DI + k0 + cbase + q*4];
        xcs[r][cbase + q*4 + 0] = v.x; xcs[r][cbase + q*4 + 1] = v.y;
        xcs[r][cbase + q*4 + 2] = v.z; xcs[r][cbase + q*4 + 3] = v.w;
      }
    }
    for (int idx = threadIdx.x; idx < 36 * 16; idx += 256) {
      int j = idx >> 4; int cc = (idx & 15) << 2;
      float4 v = make_float4(0.f, 0.f, 0.f, 0.f);
      if (j < 33) v = *(const float4*)&Wxp[(size_t)j * DI + k0 + cc];
      *(float4*)&Ws[j][cc] = v;
    }
    __syncthreads();
#pragma unroll 4
    for (int kk = 0; kk < 64; kk += 4) {
      float4 wr[9];
#pragma unroll
      for (int jj = 0; jj < 9; ++jj) wr[jj] = *(const float4*)&Ws[wv*9 + jj][kk];
      float a0 = xcs[lane][kk+0], a1 = xcs[lane][kk+1];
      float a2 = xcs[lane][kk+2], a3 = xcs[lane][kk+3];
#pragma unroll
      for (int jj = 0; jj < 9; ++jj) {
        acc[jj] = fmaf(a0, wr[jj].x, acc[jj]);
        acc[jj] = fmaf(a1, wr[jj].y, acc[jj]);
        acc[jj] = fmaf(a2, wr[jj].z, acc[jj]);
        acc[jj] = fmaf(a3, wr[jj].w, acc[jj]);
      }
    }
    __syncthreads();
  }
  const int l = L0 + lane;
#pragma unroll
  for (int jj = 0; jj < 9; ++jj) {
    int j = wv * 9 + jj;
    if (j < 33)
      xp_part[(size_t)ks * L_SEQ * XP_LD + (size_t)l * XP_LD + j] = acc[jj];
  }
}

// ---------------------------------------------------------------------------
// Reduce split-K partials: xp = sum_ks xp_part[ks].
// ---------------------------------------------------------------------------
__global__ __launch_bounds__(256) void reduce_xp_k(
    const float* __restrict__ part, float* __restrict__ xp) {
  int i = blockIdx.x * 256 + threadIdx.x;
  float s = 0.f;
#pragma unroll
  for (int ks = 0; ks < KSPLIT; ++ks)
    s += part[(size_t)ks * L_SEQ * XP_LD + i];
  xp[i] = s;
}

// ---------------------------------------------------------------------------
// LDS staging for scan: xps row = [B 0..15 | C 16..31 | dtr 32], stride 36.
// ---------------------------------------------------------------------------
__device__ __forceinline__ void stage_xps(
    float (*xps)[36], const float* __restrict__ xp, int l0, int tid) {
  for (int idx = tid; idx < LC * 33; idx += 256) {
    int rr = idx / 33, j = idx - rr * 33;
    int col = (j == 0) ? 32 : j - 1;
    xps[rr][col] = xp[(size_t)(l0 + rr) * XP_LD + j];
  }
}

// ---------------------------------------------------------------------------
// Coalesced xcT chunk staging: xcs[128 d][LC t] (pad 33).
// ---------------------------------------------------------------------------
__device__ __forceinline__ void stage_xcs(
    float (*xcs)[LC + 1], const float* __restrict__ xcT, int d0, int l0, int tid) {
#pragma unroll
  for (int q = 0; q < 4; ++q) {
    int f4  = q * 256 + tid;            // 0..1023
    int row = f4 >> 3;                  // 0..127
    int col = (f4 & 7) * 4;             // 0..28
    float4 v = *(const float4*)&xcT[(size_t)(d0 + row) * L_SEQ + l0 + col];
    xcs[row][col+0] = v.x; xcs[row][col+1] = v.y;
    xcs[row][col+2] = v.z; xcs[row][col+3] = v.w;
  }
}

// ---------------------------------------------------------------------------
// Scan phase A: per-chunk local scan from h=0, n-split x2 (8 states/thread).
// Q = h_end accumulated in-loop; P = exp2(Ad2 * sum(dt)) closed-form.
// grid = (DI/128, NCHUNK), 256 thr.
// ---------------------------------------------------------------------------
__global__ __launch_bounds__(256) void scan_partial_k(
    const float* __restrict__ xcT, const float* __restrict__ xp,
    const float* __restrict__ dtw, const float* __restrict__ dtb,
    const float* __restrict__ A_log,
    float* __restrict__ P, float* __restrict__ Q) {
  const int tid = threadIdx.x;
  const int dl  = tid >> 1;
  const int d0  = blockIdx.x * 128;
  const int d   = d0 + dl;
  const int nb  = (tid & 1) * 8;
  const int c   = blockIdx.y;
  const int l0  = c * LC;
  __shared__ float xps[LC][36];
  __shared__ float xcs[128][LC + 1];
  stage_xps(xps, xp, l0, tid);
  stage_xcs(xcs, xcT, d0, l0, tid);

  float Ad2[8];   // -exp(A_log) * log2(e)  ->  da = exp2(dt * Ad2)
#pragma unroll
  for (int j4 = 0; j4 < 8; j4 += 4) {
    float4 v = *(const float4*)&A_log[(size_t)d * NST + nb + j4];
    Ad2[j4+0] = -__expf(v.x) * LOG2E; Ad2[j4+1] = -__expf(v.y) * LOG2E;
    Ad2[j4+2] = -__expf(v.z) * LOG2E; Ad2[j4+3] = -__expf(v.w) * LOG2E;
  }
  const float w = dtw[d], b = dtb[d];
  float h[8];
#pragma unroll
  for (int n = 0; n < 8; ++n) h[n] = 0.f;
  float sumdt = 0.f;
  __syncthreads();
#pragma unroll 4
  for (int t = 0; t < LC; ++t) {
    float dt  = softplus_f(fmaf(xps[t][32], w, b));
    sumdt += dt;
    float dtx = dt * xcs[dl][t];
    f32x4 B0 = *(const f32x4*)&xps[t][nb];
    f32x4 B1 = *(const f32x4*)&xps[t][nb + 4];
    float Bv[8];
    *(f32x4*)&Bv[0] = B0; *(f32x4*)&Bv[4] = B1;
#pragma unroll
    for (int n = 0; n < 8; ++n) {
      float da = exp2f(dt * Ad2[n]);
      h[n] = fmaf(da, h[n], dtx * Bv[n]);
    }
  }
  float p[8];
#pragma unroll
  for (int n = 0; n < 8; ++n) p[n] = exp2f(sumdt * Ad2[n]);
  size_t base = ((size_t)c * DI + d) * NST + nb;
  *(float4*)&P[base]     = make_float4(p[0], p[1], p[2], p[3]);
  *(float4*)&P[base + 4] = make_float4(p[4], p[5], p[6], p[7]);
  *(float4*)&Q[base]     = make_float4(h[0], h[1], h[2], h[3]);
  *(float4*)&Q[base + 4] = make_float4(h[4], h[5], h[6], h[7]);
}

// ---------------------------------------------------------------------------
// Scan phase B: sequential prefix over chunks, thread per (d, n4).
// QHs transformed IN PLACE: Q[c] (h_end local) -> Hs[c] (h_start global).
// ---------------------------------------------------------------------------
__global__ __launch_bounds__(256) void scan_prefix_k(
    const float* __restrict__ P, float* __restrict__ QHs) {
  const int g = blockIdx.x * 256 + threadIdx.x;   // 0..8191
  const int d = g >> 2;
  const int q = (g & 3) << 2;
  float4 h = make_float4(0.f, 0.f, 0.f, 0.f);
#pragma unroll 8
  for (int c = 0; c < NCHUNK; ++c) {
    size_t base = ((size_t)c * DI + d) * NST + q;
    float4 pv = *(const float4*)&P[base];
    float4 qv = *(const float4*)&QHs[base];
    *(float4*)&QHs[base] = h;
    h.x = fmaf(pv.x, h.x, qv.x);
    h.y = fmaf(pv.y, h.y, qv.y);
    h.z = fmaf(pv.z, h.z, qv.z);
    h.w = fmaf(pv.w, h.w, qv.w);
  }
}

// ---------------------------------------------------------------------------
// Scan phase C: seeded re-scan, n-split x2; y reduced via shfl_xor(1).
// ys (bf16) = (scan_y + xc*D) * silu(z).  grid = (DI/128, NCHUNK).
// ---------------------------------------------------------------------------
__global__ __launch_bounds__(256) void scan_final_k(
    const float* __restrict__ xcT, const float* __restrict__ xp,
    const float* __restrict__ dtw, const float* __restrict__ dtb,
    const float* __restrict__ A_log, const float* __restrict__ Dp,
    const float* __restrict__ Hs, const float* __restrict__ xz,
    ushort* __restrict__ ys) {
  const int tid  = threadIdx.x;
  const int dl   = tid >> 1;
  const int d0   = blockIdx.x * 128;
  const int d    = d0 + dl;
  const int half = tid & 1;
  const int nb   = half * 8;
  const int c    = blockIdx.y;
  const int l0   = c * LC;
  __shared__ float xps[LC][36];
  __shared__ float xcs[128][LC + 1];
  __shared__ float zs[LC][128];     // [t][d], linear for global_load_lds
#pragma unroll
  for (int q = 0; q < 4; ++q) {
    int id = q * 256 + tid;
    int t  = id >> 5;
    int c4 = (id & 31) * 4;
    gload_lds16(xz + (size_t)(l0 + t) * 4096 + 2048 + d0 + c4,
                (char*)zs + id * 16);
  }
  stage_xps(xps, xp, l0, tid);
  stage_xcs(xcs, xcT, d0, l0, tid);

  float Ad2[8];
#pragma unroll
  for (int j4 = 0; j4 < 8; j4 += 4) {
    float4 v = *(const float4*)&A_log[(size_t)d * NST + nb + j4];
    Ad2[j4+0] = -__expf(v.x) * LOG2E; Ad2[j4+1] = -__expf(v.y) * LOG2E;
    Ad2[j4+2] = -__expf(v.z) * LOG2E; Ad2[j4+3] = -__expf(v.w) * LOG2E;
  }
  const float w = dtw[d], b = dtb[d], Dd = Dp[d];
  float h[8];
  size_t hb = ((size_t)c * DI + d) * NST + nb;
  *(float4*)&h[0] = *(const float4*)&Hs[hb];
  *(float4*)&h[4] = *(const float4*)&Hs[hb + 4];
  __syncthreads();    // also drains the global_load_lds (vmcnt) per G-contract
#pragma unroll 4
  for (int t = 0; t < LC; ++t) {
    const int l = l0 + t;
    float dt  = softplus_f(fmaf(xps[t][32], w, b));
    float xcv = xcs[dl][t];
    float dtx = dt * xcv;
    f32x4 B0 = *(const f32x4*)&xps[t][nb];
    f32x4 B1 = *(const f32x4*)&xps[t][nb + 4];
    f32x4 C0 = *(const f32x4*)&xps[t][16 + nb];
    f32x4 C1 = *(const f32x4*)&xps[t][20 + nb];
    float Bv[8], Cv[8];
    *(f32x4*)&Bv[0] = B0; *(f32x4*)&Bv[4] = B1;
    *(f32x4*)&Cv[0] = C0; *(f32x4*)&Cv[4] = C1;
    float y = 0.f;
#pragma unroll
    for (int n = 0; n < 8; ++n) {
      float da = exp2f(dt * Ad2[n]);
      h[n] = fmaf(da, h[n], dtx * Bv[n]);
      y = fmaf(h[n], Cv[n], y);
    }
    y += __shfl_xor(y, 1);
    if (half == 0) {
      y = fmaf(xcv, Dd, y);
      ys[(size_t)l * DI + d] = f2bf(y * silu_f(zs[t][dl]));
    }
  }
}

// ---------------------------------------------------------------------------
extern "C" void kernel_launch(void* const* d_in, const int* in_sizes, int n_in,
                              void* d_out, int out_size, void* d_ws, size_t ws_size,
                              hipStream_t stream) {
  const float* x    = (const float*)d_in[0];   // (2048,1024)
  const float* W1   = (const float*)d_in[1];   // (4096,1024)
  const float* cw   = (const float*)d_in[2];   // (2048,1,4)
  const float* cb   = (const float*)d_in[3];   // (2048,)
  const float* Wxp  = (const float*)d_in[4];   // (33,2048)
  const float* dtw  = (const float*)d_in[5];   // (2048,1)
  const float* dtb  = (const float*)d_in[6];   // (2048,)
  const float* Alog = (const float*)d_in[7];   // (2048,16)
  const float* Dp   = (const float*)d_in[8];   // (2048,)
  const float* Wout = (const float*)d_in[9];   // (1024,2048)
  float* out = (float*)d_out;                  // (2048,1024)

  char* w = (char*)d_ws;
  float*  xz      = (float*)w;                    // [0, 33554432)
  float*  xcT     = (float*)(w + 33554432);       // [33554432, 50331648)  (d, l)
  // --- region [50331648, 67108864): xc row-major; aliased before by
  //     x_bf/W1_bf (dead after GEMM1), after gemm_xp by P/QHs ---
  float*  xc_rm   = (float*)(w + 50331648);       // 16,777,216 B
  ushort* x_bf    = (ushort*)(w + 50331648);      //  4 MiB
  ushort* W1_bf   = (ushort*)(w + 54525952);      //  8 MiB
  float*  P       = (float*)(w + 50331648);       //  8,388,608 B
  float*  QHs     = (float*)(w + 58720256);       //  8,388,608 B
  // --- persistent tail ---
  float*  xp      = (float*)(w + 67108864);       //    294,912 B
  ushort* Wout_bf = (ushort*)(w + 67403776);      //  4 MiB
  ushort* ys_bf   = (ushort*)(w + 71598080);      //  8 MiB (aliased early by xp_part)
  float*  xp_part = (float*)(w + 71598080);       //  2,359,296 B, dead before scan_final
  // total = 79,986,688 B

  // 0. fp32 -> bf16 conversions
  cvt_bf16_k<<<2048, 256, 0, stream>>>(x,    x_bf,    2048*1024/4);
  cvt_bf16_k<<<4096, 256, 0, stream>>>(W1,   W1_bf,   4096*1024/4);
  cvt_bf16_k<<<2048, 256, 0, stream>>>(Wout, Wout_bf, 1024*2048/4);
  // 1. xz = x @ in_proj_w^T   (MFMA bf16)
  gemm_mfma_bf16<4><<<dim3(4096/128, 2048/128), 256, 0, stream>>>(x_bf, W1_bf, xz, DM, 4096);
  // 2. depthwise conv + silu  (writes xc row-major; x_bf/W1_bf now dead)
  conv_silu_k<<<dim3(DI/256, L_SEQ), 256, 0, stream>>>(xz, cw, cb, xc_rm);
  // 2b. transpose to (d, l) for the scan
  transpose_k<<<dim3(DI/64, L_SEQ/64), 256, 0, stream>>>(xc_rm, xcT);
  // 3. xp = xc @ x_proj_w^T  (split-K partials + reduce)
  gemm_xp_k<<<dim3(L_SEQ/64, KSPLIT), 256, 0, stream>>>(xc_rm, Wxp, xp_part);
  reduce_xp_k<<<L_SEQ*XP_LD/256, 256, 0, stream>>>(xp_part, xp);
  // 4. chunked selective scan (xc_rm dead; P/QHs reuse its region)
  scan_partial_k<<<dim3(DI/128, NCHUNK), 256, 0, stream>>>(xcT, xp, dtw, dtb, Alog, P, QHs);
  scan_prefix_k<<<DI*NST/4/256, 256, 0, stream>>>(P, QHs);
  scan_final_k<<<dim3(DI/128, NCHUNK), 256, 0, stream>>>(xcT, xp, dtw, dtb, Alog, Dp, QHs, xz, ys_bf);
  // 5. out = ys @ out_proj_w^T   (MFMA bf16, BM=64 for 256-block grid)
  gemm_mfma_bf16<2><<<dim3(1024/128, 2048/64), 256, 0, stream>>>(ys_bf, Wout_bf, out, DI, 1024);
}

// Round 10
// 264.919 us; speedup vs baseline: 1.6220x; 1.0524x over previous
//
#include <hip/hip_runtime.h>
#include <math.h>

#define L_SEQ   2048
#define DM      1024
#define DI      2048
#define NST     16
#define LC      32      // chunk length for scan
#define NCHUNK  64      // L_SEQ / LC
#define XP_LD   36      // padded leading dim for xp (33 cols)
#define KSPLIT  8       // K-splits for gemm_xp
#define LOG2E   1.44269504f

typedef short s16x8 __attribute__((ext_vector_type(8)));
typedef unsigned short u16x8 __attribute__((ext_vector_type(8)));
typedef float f32x4 __attribute__((ext_vector_type(4)));

__device__ __forceinline__ float silu_f(float x) {
  return x / (1.0f + __expf(-x));
}
// fast softplus (arg regime safe; threshold 0.155 >> err)
__device__ __forceinline__ float softplus_f(float x) {
  return x > 20.0f ? x : __logf(1.0f + __expf(x));
}
__device__ __forceinline__ ushort f2bf(float f) {
  unsigned int u = __float_as_uint(f);
  unsigned int r = (u + 0x7fffu + ((u >> 16) & 1u)) >> 16;
  return (ushort)r;
}
__device__ __forceinline__ float bf2f(ushort u) {
  return __uint_as_float((unsigned int)u << 16);
}
__device__ __forceinline__ void gload_lds16(const void* g, void* lds) {
  __builtin_amdgcn_global_load_lds(
      (const __attribute__((address_space(1))) unsigned int*)g,
      (__attribute__((address_space(3))) unsigned int*)lds,
      16, 0, 0);
}

// ---------------------------------------------------------------------------
// fp32 -> bf16 conversion, 4 elems/thread
// ---------------------------------------------------------------------------
__global__ __launch_bounds__(256) void cvt_bf16_k(
    const float* __restrict__ in, ushort* __restrict__ out, int n4) {
  int i = blockIdx.x * 256 + threadIdx.x;
  if (i >= n4) return;
  float4 v = ((const float4*)in)[i];
  ushort4 o;
  o.x = f2bf(v.x); o.y = f2bf(v.y); o.z = f2bf(v.z); o.w = f2bf(v.w);
  ((ushort4*)out)[i] = o;
}

// ---------------------------------------------------------------------------
// bf16 MFMA GEMM: C = A(MxK,row) * B(NxK,row)^T.  Output fp32 or bf16.
// m97 structure: BK=32, 4 waves (2x2), BM = MFRAG*32, BN = 128.
// ---------------------------------------------------------------------------
template <int MFRAG, bool BF16OUT>
__global__ __launch_bounds__(256) void gemm_mfma_bf16(
    const ushort* __restrict__ A, const ushort* __restrict__ B,
    void* __restrict__ Cv, int K, int ldc) {
  constexpr int BM = MFRAG * 32;
  __shared__ ushort As[BM * 32];
  __shared__ ushort Bs[128 * 32];
  const int tid  = threadIdx.x;
  const int lane = tid & 63;
  const int wv   = tid >> 6;
  const int wr   = wv >> 1;
  const int wc   = wv & 1;
  const int m0 = blockIdx.y * BM;
  const int n0 = blockIdx.x * 128;

  f32x4 acc[MFRAG][4] = {};
  const int kc = (tid & 3) * 8;

  for (int k0 = 0; k0 < K; k0 += 32) {
    __syncthreads();
#pragma unroll
    for (int q = 0; q < BM / 64; ++q) {
      int id = q * 256 + tid;
      int m  = id >> 2;
      gload_lds16(A + (size_t)(m0 + m) * K + k0 + kc, (char*)As + id * 16);
    }
#pragma unroll
    for (int q = 0; q < 2; ++q) {
      int id = q * 256 + tid;
      int n  = id >> 2;
      gload_lds16(B + (size_t)(n0 + n) * K + k0 + kc, (char*)Bs + id * 16);
    }
    __syncthreads();

    s16x8 af[MFRAG], bfr[4];
#pragma unroll
    for (int m = 0; m < MFRAG; ++m)
      af[m] = *(const s16x8*)&As[(wr * MFRAG * 16 + m * 16 + (lane & 15)) * 32 + (lane >> 4) * 8];
#pragma unroll
    for (int n = 0; n < 4; ++n)
      bfr[n] = *(const s16x8*)&Bs[(wc * 64 + n * 16 + (lane & 15)) * 32 + (lane >> 4) * 8];
#pragma unroll
    for (int m = 0; m < MFRAG; ++m)
#pragma unroll
      for (int n = 0; n < 4; ++n)
        acc[m][n] = __builtin_amdgcn_mfma_f32_16x16x32_bf16(af[m], bfr[n], acc[m][n], 0, 0, 0);
  }
  const int cr = (lane >> 4) * 4;
  const int cc = lane & 15;
#pragma unroll
  for (int m = 0; m < MFRAG; ++m) {
    int gr0 = m0 + wr * MFRAG * 16 + m * 16 + cr;
#pragma unroll
    for (int n = 0; n < 4; ++n) {
      int gc = n0 + wc * 64 + n * 16 + cc;
#pragma unroll
      for (int r = 0; r < 4; ++r) {
        if constexpr (BF16OUT)
          ((ushort*)Cv)[(size_t)(gr0 + r) * ldc + gc] = f2bf(acc[m][n][r]);
        else
          ((float*)Cv)[(size_t)(gr0 + r) * ldc + gc] = acc[m][n][r];
      }
    }
  }
}

// ---------------------------------------------------------------------------
// Fused depthwise conv (D_CONV=4) + bias + silu + transpose.
// Reads xz bf16 (L,4096) x_ssm half; writes xcT fp32 (d,l) coalescedly.
// grid = (DI/64, L/64), 256 thr.
// ---------------------------------------------------------------------------
__global__ __launch_bounds__(256) void conv_silu_T_k(
    const ushort* __restrict__ xzb, const float* __restrict__ cw,
    const float* __restrict__ cb, float* __restrict__ xcT) {
  const int d0  = blockIdx.x * 64;
  const int l0  = blockIdx.y * 64;
  const int tid = threadIdx.x;
  __shared__ ushort xt[67][64];   // rows l0-3 .. l0+63
  __shared__ float  ot[64][65];   // [d][l] out tile
  // load 67 x 64 bf16 (16B chunks)
#pragma unroll
  for (int q = 0; q < 3; ++q) {
    int id = q * 256 + tid;
    if (id < 67 * 8) {
      int row = id >> 3, c8 = (id & 7) * 8;
      int l = l0 - 3 + row;
      u16x8 v = (u16x8)(ushort)0;
      if (l >= 0)
        v = *(const u16x8*)&xzb[(size_t)l * 4096 + d0 + c8];
      *(u16x8*)&xt[row][c8] = v;
    }
  }
  __syncthreads();
  const int dloc = tid & 63;
  const int d    = d0 + dloc;
  const float w0 = cw[d*4+0], w1 = cw[d*4+1], w2 = cw[d*4+2], w3 = cw[d*4+3];
  const float bb = cb[d];
  const int lb = (tid >> 6) * 16;
#pragma unroll
  for (int j = 0; j < 16; ++j) {
    int ll = lb + j;                 // output l = l0 + ll
    float a = bb;
    a = fmaf(w0, bf2f(xt[ll+0][dloc]), a);
    a = fmaf(w1, bf2f(xt[ll+1][dloc]), a);
    a = fmaf(w2, bf2f(xt[ll+2][dloc]), a);
    a = fmaf(w3, bf2f(xt[ll+3][dloc]), a);
    ot[dloc][ll] = silu_f(a);
  }
  __syncthreads();
#pragma unroll
  for (int q = 0; q < 4; ++q) {
    int f4 = q * 256 + tid;
    int dr = f4 >> 4, lc = (f4 & 15) * 4;
    float4 v = make_float4(ot[dr][lc], ot[dr][lc+1], ot[dr][lc+2], ot[dr][lc+3]);
    *(float4*)&xcT[(size_t)(d0 + dr) * L_SEQ + l0 + lc] = v;
  }
}

// ---------------------------------------------------------------------------
// xp partials from xcT: split-K, transposed LDS staging.
// grid = (L/64, KSPLIT).
// ---------------------------------------------------------------------------
__global__ __launch_bounds__(256) void gemm_xp_k(
    const float* __restrict__ xcT, const float* __restrict__ Wxp,
    float* __restrict__ xp_part) {
  const int L0   = blockIdx.x * 64;
  const int ks   = blockIdx.y;
  const int wv   = threadIdx.x >> 6;
  const int lane = threadIdx.x & 63;
  __shared__ float xcs[64][65];    // [l][k]
  __shared__ float Ws[36][64];
  float acc[9] = {};
  const int kbeg = ks * (DI / KSPLIT);
  const int kend = kbeg + DI / KSPLIT;
  for (int k0 = kbeg; k0 < kend; k0 += 64) {
#pragma unroll
    for (int q = 0; q < 4; ++q) {
      int f4 = q * 256 + threadIdx.x;
      int dr = f4 >> 4;              // k row 0..63
      int lc = (f4 & 15) * 4;        // l col
      float4 v = *(const float4*)&xcT[(size_t)(k0 + dr) * L_SEQ + L0 + lc];
      xcs[lc+0][dr] = v.x; xcs[lc+1][dr] = v.y;
      xcs[lc+2][dr] = v.z; xcs[lc+3][dr] = v.w;
    }
    for (int idx = threadIdx.x; idx < 36 * 16; idx += 256) {
      int j = idx >> 4; int cc = (idx & 15) << 2;
      float4 v = make_float4(0.f, 0.f, 0.f, 0.f);
      if (j < 33) v = *(const float4*)&Wxp[(size_t)j * DI + k0 + cc];
      *(float4*)&Ws[j][cc] = v;
    }
    __syncthreads();
#pragma unroll 4
    for (int kk = 0; kk < 64; kk += 4) {
      float4 wr[9];
#pragma unroll
      for (int jj = 0; jj < 9; ++jj) wr[jj] = *(const float4*)&Ws[wv*9 + jj][kk];
      float a0 = xcs[lane][kk+0], a1 = xcs[lane][kk+1];
      float a2 = xcs[lane][kk+2], a3 = xcs[lane][kk+3];
#pragma unroll
      for (int jj = 0; jj < 9; ++jj) {
        acc[jj] = fmaf(a0, wr[jj].x, acc[jj]);
        acc[jj] = fmaf(a1, wr[jj].y, acc[jj]);
        acc[jj] = fmaf(a2, wr[jj].z, acc[jj]);
        acc[jj] = fmaf(a3, wr[jj].w, acc[jj]);
      }
    }
    __syncthreads();
  }
  const int l = L0 + lane;
#pragma unroll
  for (int jj = 0; jj < 9; ++jj) {
    int j = wv * 9 + jj;
    if (j < 33)
      xp_part[(size_t)ks * L_SEQ * XP_LD + (size_t)l * XP_LD + j] = acc[jj];
  }
}

// ---------------------------------------------------------------------------
// Reduce split-K partials: xp = sum_ks xp_part[ks].
// ---------------------------------------------------------------------------
__global__ __launch_bounds__(256) void reduce_xp_k(
    const float* __restrict__ part, float* __restrict__ xp) {
  int i = blockIdx.x * 256 + threadIdx.x;
  float s = 0.f;
#pragma unroll
  for (int ks = 0; ks < KSPLIT; ++ks)
    s += part[(size_t)ks * L_SEQ * XP_LD + i];
  xp[i] = s;
}

// ---------------------------------------------------------------------------
// LDS staging for scan: xps row = [B 0..15 | C 16..31 | dtr 32], stride 36.
// ---------------------------------------------------------------------------
__device__ __forceinline__ void stage_xps(
    float (*xps)[36], const float* __restrict__ xp, int l0, int tid) {
  for (int idx = tid; idx < LC * 33; idx += 256) {
    int rr = idx / 33, j = idx - rr * 33;
    int col = (j == 0) ? 32 : j - 1;
    xps[rr][col] = xp[(size_t)(l0 + rr) * XP_LD + j];
  }
}
// Coalesced xcT chunk staging: xcs[128 d][LC t] (pad 33).
__device__ __forceinline__ void stage_xcs(
    float (*xcs)[LC + 1], const float* __restrict__ xcT, int d0, int l0, int tid) {
#pragma unroll
  for (int q = 0; q < 4; ++q) {
    int f4  = q * 256 + tid;
    int row = f4 >> 3;
    int col = (f4 & 7) * 4;
    float4 v = *(const float4*)&xcT[(size_t)(d0 + row) * L_SEQ + l0 + col];
    xcs[row][col+0] = v.x; xcs[row][col+1] = v.y;
    xcs[row][col+2] = v.z; xcs[row][col+3] = v.w;
  }
}
// dt precompute: dts[t][d] = softplus(dtr[t]*w[d]+b[d]); one d per thread.
__device__ __forceinline__ void stage_dts(
    float (*dts)[128], float (*xps)[36],
    const float* __restrict__ dtw, const float* __restrict__ dtb,
    int d0, int tid) {
  int dd = tid & 127;
  int tb = (tid >> 7) * 16;
  float wv = dtw[d0 + dd], bv = dtb[d0 + dd];
#pragma unroll
  for (int j = 0; j < 16; ++j)
    dts[tb + j][dd] = softplus_f(fmaf(xps[tb + j][32], wv, bv));
}

// ---------------------------------------------------------------------------
// Scan phase A: local scan from h=0, n-split x2 (8 states/thread).
// dt's hoisted to LDS (breaks softplus dep chain).  P closed-form.
// grid = (DI/128, NCHUNK), 256 thr.
// ---------------------------------------------------------------------------
__global__ __launch_bounds__(256) void scan_partial_k(
    const float* __restrict__ xcT, const float* __restrict__ xp,
    const float* __restrict__ dtw, const float* __restrict__ dtb,
    const float* __restrict__ A_log,
    float* __restrict__ P, float* __restrict__ Q) {
  const int tid = threadIdx.x;
  const int dl  = tid >> 1;
  const int d0  = blockIdx.x * 128;
  const int d   = d0 + dl;
  const int nb  = (tid & 1) * 8;
  const int c   = blockIdx.y;
  const int l0  = c * LC;
  __shared__ float xps[LC][36];
  __shared__ float xcs[128][LC + 1];
  __shared__ float dts[LC][128];
  stage_xps(xps, xp, l0, tid);
  stage_xcs(xcs, xcT, d0, l0, tid);

  float Ad2[8];   // -exp(A_log)*log2e
#pragma unroll
  for (int j4 = 0; j4 < 8; j4 += 4) {
    float4 v = *(const float4*)&A_log[(size_t)d * NST + nb + j4];
    Ad2[j4+0] = -__expf(v.x) * LOG2E; Ad2[j4+1] = -__expf(v.y) * LOG2E;
    Ad2[j4+2] = -__expf(v.z) * LOG2E; Ad2[j4+3] = -__expf(v.w) * LOG2E;
  }
  __syncthreads();
  stage_dts(dts, xps, dtw, dtb, d0, tid);
  float h[8];
#pragma unroll
  for (int n = 0; n < 8; ++n) h[n] = 0.f;
  float sumdt = 0.f;
  __syncthreads();
#pragma unroll 4
  for (int t = 0; t < LC; ++t) {
    float dt  = dts[t][dl];
    sumdt += dt;
    float dtx = dt * xcs[dl][t];
    f32x4 B0 = *(const f32x4*)&xps[t][nb];
    f32x4 B1 = *(const f32x4*)&xps[t][nb + 4];
    float Bv[8];
    *(f32x4*)&Bv[0] = B0; *(f32x4*)&Bv[4] = B1;
#pragma unroll
    for (int n = 0; n < 8; ++n) {
      float da = exp2f(dt * Ad2[n]);
      h[n] = fmaf(da, h[n], dtx * Bv[n]);
    }
  }
  float p[8];
#pragma unroll
  for (int n = 0; n < 8; ++n) p[n] = exp2f(sumdt * Ad2[n]);
  size_t base = ((size_t)c * DI + d) * NST + nb;
  *(float4*)&P[base]     = make_float4(p[0], p[1], p[2], p[3]);
  *(float4*)&P[base + 4] = make_float4(p[4], p[5], p[6], p[7]);
  *(float4*)&Q[base]     = make_float4(h[0], h[1], h[2], h[3]);
  *(float4*)&Q[base + 4] = make_float4(h[4], h[5], h[6], h[7]);
}

// ---------------------------------------------------------------------------
// Scan phase B: sequential prefix over chunks, thread per (d, n4).
// QHs transformed IN PLACE: Q[c] -> h_start[c].
// ---------------------------------------------------------------------------
__global__ __launch_bounds__(256) void scan_prefix_k(
    const float* __restrict__ P, float* __restrict__ QHs) {
  const int g = blockIdx.x * 256 + threadIdx.x;
  const int d = g >> 2;
  const int q = (g & 3) << 2;
  float4 h = make_float4(0.f, 0.f, 0.f, 0.f);
#pragma unroll 8
  for (int c = 0; c < NCHUNK; ++c) {
    size_t base = ((size_t)c * DI + d) * NST + q;
    float4 pv = *(const float4*)&P[base];
    float4 qv = *(const float4*)&QHs[base];
    *(float4*)&QHs[base] = h;
    h.x = fmaf(pv.x, h.x, qv.x);
    h.y = fmaf(pv.y, h.y, qv.y);
    h.z = fmaf(pv.z, h.z, qv.z);
    h.w = fmaf(pv.w, h.w, qv.w);
  }
}

// ---------------------------------------------------------------------------
// Scan phase C: seeded re-scan; dt's hoisted; z (bf16) via global_load_lds.
// ys (bf16) = (scan_y + xc*D) * silu(z).  grid = (DI/128, NCHUNK).
// ---------------------------------------------------------------------------
__global__ __launch_bounds__(256) void scan_final_k(
    const float* __restrict__ xcT, const float* __restrict__ xp,
    const float* __restrict__ dtw, const float* __restrict__ dtb,
    const float* __restrict__ A_log, const float* __restrict__ Dp,
    const float* __restrict__ Hs, const ushort* __restrict__ xzb,
    ushort* __restrict__ ys) {
  const int tid  = threadIdx.x;
  const int dl   = tid >> 1;
  const int d0   = blockIdx.x * 128;
  const int d    = d0 + dl;
  const int half = tid & 1;
  const int nb   = half * 8;
  const int c    = blockIdx.y;
  const int l0   = c * LC;
  __shared__ float  xps[LC][36];
  __shared__ float  xcs[128][LC + 1];
  __shared__ float  dts[LC][128];
  __shared__ ushort zs[LC][128];    // bf16, linear for global_load_lds
#pragma unroll
  for (int q = 0; q < 2; ++q) {
    int id = q * 256 + tid;         // 16B = 8 bf16
    int t  = id >> 4;
    int c8 = (id & 15) * 8;
    gload_lds16(xzb + (size_t)(l0 + t) * 4096 + 2048 + d0 + c8,
                (char*)zs + id * 16);
  }
  stage_xps(xps, xp, l0, tid);
  stage_xcs(xcs, xcT, d0, l0, tid);

  float Ad2[8];
#pragma unroll
  for (int j4 = 0; j4 < 8; j4 += 4) {
    float4 v = *(const float4*)&A_log[(size_t)d * NST + nb + j4];
    Ad2[j4+0] = -__expf(v.x) * LOG2E; Ad2[j4+1] = -__expf(v.y) * LOG2E;
    Ad2[j4+2] = -__expf(v.z) * LOG2E; Ad2[j4+3] = -__expf(v.w) * LOG2E;
  }
  const float Dd = Dp[d];
  float h[8];
  size_t hb = ((size_t)c * DI + d) * NST + nb;
  *(float4*)&h[0] = *(const float4*)&Hs[hb];
  *(float4*)&h[4] = *(const float4*)&Hs[hb + 4];
  __syncthreads();    // drains gload_lds + xps staged
  stage_dts(dts, xps, dtw, dtb, d0, tid);
  __syncthreads();
#pragma unroll 4
  for (int t = 0; t < LC; ++t) {
    const int l = l0 + t;
    float dt  = dts[t][dl];
    float xcv = xcs[dl][t];
    float dtx = dt * xcv;
    f32x4 B0 = *(const f32x4*)&xps[t][nb];
    f32x4 B1 = *(const f32x4*)&xps[t][nb + 4];
    f32x4 C0 = *(const f32x4*)&xps[t][16 + nb];
    f32x4 C1 = *(const f32x4*)&xps[t][20 + nb];
    float Bv[8], Cv[8];
    *(f32x4*)&Bv[0] = B0; *(f32x4*)&Bv[4] = B1;
    *(f32x4*)&Cv[0] = C0; *(f32x4*)&Cv[4] = C1;
    float y = 0.f;
#pragma unroll
    for (int n = 0; n < 8; ++n) {
      float da = exp2f(dt * Ad2[n]);
      h[n] = fmaf(da, h[n], dtx * Bv[n]);
      y = fmaf(h[n], Cv[n], y);
    }
    y += __shfl_xor(y, 1);
    if (half == 0) {
      y = fmaf(xcv, Dd, y);
      ys[(size_t)l * DI + d] = f2bf(y * silu_f(bf2f(zs[t][dl])));
    }
  }
}

// ---------------------------------------------------------------------------
extern "C" void kernel_launch(void* const* d_in, const int* in_sizes, int n_in,
                              void* d_out, int out_size, void* d_ws, size_t ws_size,
                              hipStream_t stream) {
  const float* x    = (const float*)d_in[0];
  const float* W1   = (const float*)d_in[1];
  const float* cw   = (const float*)d_in[2];
  const float* cb   = (const float*)d_in[3];
  const float* Wxp  = (const float*)d_in[4];
  const float* dtw  = (const float*)d_in[5];
  const float* dtb  = (const float*)d_in[6];
  const float* Alog = (const float*)d_in[7];
  const float* Dp   = (const float*)d_in[8];
  const float* Wout = (const float*)d_in[9];
  float* out = (float*)d_out;

  char* w = (char*)d_ws;
  ushort* xz_bf   = (ushort*)w;                   // [0, 16777216)  (L,4096) bf16
  float*  xcT     = (float*)(w + 16777216);       // [16777216, 33554432)  (d,l) f32
  // region C [33554432, 50331648): x_bf+W1_bf early; P+QHs after GEMM1
  ushort* x_bf    = (ushort*)(w + 33554432);      //  4 MiB
  ushort* W1_bf   = (ushort*)(w + 37748736);      //  8 MiB
  float*  P       = (float*)(w + 33554432);       //  8,388,608 B
  float*  QHs     = (float*)(w + 41943040);       //  8,388,608 B
  // persistent tail
  float*  xp      = (float*)(w + 50331648);       //    294,912 B
  ushort* Wout_bf = (ushort*)(w + 50626560);      //  4 MiB
  ushort* ys_bf   = (ushort*)(w + 54820864);      //  8 MiB (xp_part aliases early)
  float*  xp_part = (float*)(w + 54820864);       //  2,359,296 B, dead pre-scan_final
  // total = 63,209,472 B

  // 0. input fp32 -> bf16
  cvt_bf16_k<<<2048, 256, 0, stream>>>(x,    x_bf,    2048*1024/4);
  cvt_bf16_k<<<4096, 256, 0, stream>>>(W1,   W1_bf,   4096*1024/4);
  cvt_bf16_k<<<2048, 256, 0, stream>>>(Wout, Wout_bf, 1024*2048/4);
  // 1. xz = x @ in_proj_w^T  (bf16 out)
  gemm_mfma_bf16<4, true><<<dim3(4096/128, 2048/128), 256, 0, stream>>>(
      x_bf, W1_bf, xz_bf, DM, 4096);
  // 2. fused conv + silu + transpose -> xcT (d,l)
  conv_silu_T_k<<<dim3(DI/64, L_SEQ/64), 256, 0, stream>>>(xz_bf, cw, cb, xcT);
  // 3. xp = xc @ x_proj_w^T  (split-K from xcT + reduce)
  gemm_xp_k<<<dim3(L_SEQ/64, KSPLIT), 256, 0, stream>>>(xcT, Wxp, xp_part);
  reduce_xp_k<<<L_SEQ*XP_LD/256, 256, 0, stream>>>(xp_part, xp);
  // 4. chunked selective scan
  scan_partial_k<<<dim3(DI/128, NCHUNK), 256, 0, stream>>>(xcT, xp, dtw, dtb, Alog, P, QHs);
  scan_prefix_k<<<DI*NST/4/256, 256, 0, stream>>>(P, QHs);
  scan_final_k<<<dim3(DI/128, NCHUNK), 256, 0, stream>>>(xcT, xp, dtw, dtb, Alog, Dp, QHs, xz_bf, ys_bf);
  // 5. out = ys @ out_proj_w^T  (fp32 out)
  gemm_mfma_bf16<2, false><<<dim3(1024/128, 2048/64), 256, 0, stream>>>(
      ys_bf, Wout_bf, out, DI, 1024);
}

// Round 11
// 263.324 us; speedup vs baseline: 1.6318x; 1.0061x over previous
//
#include <hip/hip_runtime.h>
#include <math.h>

#define L_SEQ   2048
#define DM      1024
#define DI      2048
#define NST     16
#define LC      32      // chunk length for scan
#define NCHUNK  64      // L_SEQ / LC
#define XP_LD   36      // padded leading dim for xp (33 cols)
#define KSPLIT  8       // K-splits for gemm_xp
#define LOG2E   1.44269504f

typedef short s16x8 __attribute__((ext_vector_type(8)));
typedef unsigned short u16x8 __attribute__((ext_vector_type(8)));
typedef float f32x4 __attribute__((ext_vector_type(4)));

__device__ __forceinline__ float silu_f(float x) {
  return x / (1.0f + __expf(-x));
}
// fast softplus (arg regime safe; threshold 0.155 >> err)
__device__ __forceinline__ float softplus_f(float x) {
  return x > 20.0f ? x : __logf(1.0f + __expf(x));
}
__device__ __forceinline__ ushort f2bf(float f) {
  unsigned int u = __float_as_uint(f);
  unsigned int r = (u + 0x7fffu + ((u >> 16) & 1u)) >> 16;
  return (ushort)r;
}
__device__ __forceinline__ float bf2f(ushort u) {
  return __uint_as_float((unsigned int)u << 16);
}
__device__ __forceinline__ void gload_lds16(const void* g, void* lds) {
  __builtin_amdgcn_global_load_lds(
      (const __attribute__((address_space(1))) unsigned int*)g,
      (__attribute__((address_space(3))) unsigned int*)lds,
      16, 0, 0);
}

// ---------------------------------------------------------------------------
// fp32 -> bf16 conversion, 4 elems/thread
// ---------------------------------------------------------------------------
__global__ __launch_bounds__(256) void cvt_bf16_k(
    const float* __restrict__ in, ushort* __restrict__ out, int n4) {
  int i = blockIdx.x * 256 + threadIdx.x;
  if (i >= n4) return;
  float4 v = ((const float4*)in)[i];
  ushort4 o;
  o.x = f2bf(v.x); o.y = f2bf(v.y); o.z = f2bf(v.z); o.w = f2bf(v.w);
  ((ushort4*)out)[i] = o;
}

// ---------------------------------------------------------------------------
// bf16 MFMA GEMM: C = A(MxK,row) * B(NxK,row)^T.  Output fp32 or bf16.
// m97 structure: BK=32, 4 waves (2x2), BM = MFRAG*32, BN = 128.
// ---------------------------------------------------------------------------
template <int MFRAG, bool BF16OUT>
__global__ __launch_bounds__(256) void gemm_mfma_bf16(
    const ushort* __restrict__ A, const ushort* __restrict__ B,
    void* __restrict__ Cv, int K, int ldc) {
  constexpr int BM = MFRAG * 32;
  __shared__ ushort As[BM * 32];
  __shared__ ushort Bs[128 * 32];
  const int tid  = threadIdx.x;
  const int lane = tid & 63;
  const int wv   = tid >> 6;
  const int wr   = wv >> 1;
  const int wc   = wv & 1;
  const int m0 = blockIdx.y * BM;
  const int n0 = blockIdx.x * 128;

  f32x4 acc[MFRAG][4] = {};
  const int kc = (tid & 3) * 8;

  for (int k0 = 0; k0 < K; k0 += 32) {
    __syncthreads();
#pragma unroll
    for (int q = 0; q < BM / 64; ++q) {
      int id = q * 256 + tid;
      int m  = id >> 2;
      gload_lds16(A + (size_t)(m0 + m) * K + k0 + kc, (char*)As + id * 16);
    }
#pragma unroll
    for (int q = 0; q < 2; ++q) {
      int id = q * 256 + tid;
      int n  = id >> 2;
      gload_lds16(B + (size_t)(n0 + n) * K + k0 + kc, (char*)Bs + id * 16);
    }
    __syncthreads();

    s16x8 af[MFRAG], bfr[4];
#pragma unroll
    for (int m = 0; m < MFRAG; ++m)
      af[m] = *(const s16x8*)&As[(wr * MFRAG * 16 + m * 16 + (lane & 15)) * 32 + (lane >> 4) * 8];
#pragma unroll
    for (int n = 0; n < 4; ++n)
      bfr[n] = *(const s16x8*)&Bs[(wc * 64 + n * 16 + (lane & 15)) * 32 + (lane >> 4) * 8];
#pragma unroll
    for (int m = 0; m < MFRAG; ++m)
#pragma unroll
      for (int n = 0; n < 4; ++n)
        acc[m][n] = __builtin_amdgcn_mfma_f32_16x16x32_bf16(af[m], bfr[n], acc[m][n], 0, 0, 0);
  }
  const int cr = (lane >> 4) * 4;
  const int cc = lane & 15;
#pragma unroll
  for (int m = 0; m < MFRAG; ++m) {
    int gr0 = m0 + wr * MFRAG * 16 + m * 16 + cr;
#pragma unroll
    for (int n = 0; n < 4; ++n) {
      int gc = n0 + wc * 64 + n * 16 + cc;
#pragma unroll
      for (int r = 0; r < 4; ++r) {
        if constexpr (BF16OUT)
          ((ushort*)Cv)[(size_t)(gr0 + r) * ldc + gc] = f2bf(acc[m][n][r]);
        else
          ((float*)Cv)[(size_t)(gr0 + r) * ldc + gc] = acc[m][n][r];
      }
    }
  }
}

// ---------------------------------------------------------------------------
// Fused depthwise conv (D_CONV=4) + bias + silu + transpose.
// Reads xz bf16 (L,4096) x_ssm half; writes xcT fp32 (d,l) coalescedly.
// grid = (DI/64, L/64), 256 thr.
// ---------------------------------------------------------------------------
__global__ __launch_bounds__(256) void conv_silu_T_k(
    const ushort* __restrict__ xzb, const float* __restrict__ cw,
    const float* __restrict__ cb, float* __restrict__ xcT) {
  const int d0  = blockIdx.x * 64;
  const int l0  = blockIdx.y * 64;
  const int tid = threadIdx.x;
  __shared__ ushort xt[67][64];   // rows l0-3 .. l0+63
  __shared__ float  ot[64][65];   // [d][l] out tile
#pragma unroll
  for (int q = 0; q < 3; ++q) {
    int id = q * 256 + tid;
    if (id < 67 * 8) {
      int row = id >> 3, c8 = (id & 7) * 8;
      int l = l0 - 3 + row;
      u16x8 v = (u16x8)(ushort)0;
      if (l >= 0)
        v = *(const u16x8*)&xzb[(size_t)l * 4096 + d0 + c8];
      *(u16x8*)&xt[row][c8] = v;
    }
  }
  __syncthreads();
  const int dloc = tid & 63;
  const int d    = d0 + dloc;
  const float w0 = cw[d*4+0], w1 = cw[d*4+1], w2 = cw[d*4+2], w3 = cw[d*4+3];
  const float bb = cb[d];
  const int lb = (tid >> 6) * 16;
#pragma unroll
  for (int j = 0; j < 16; ++j) {
    int ll = lb + j;
    float a = bb;
    a = fmaf(w0, bf2f(xt[ll+0][dloc]), a);
    a = fmaf(w1, bf2f(xt[ll+1][dloc]), a);
    a = fmaf(w2, bf2f(xt[ll+2][dloc]), a);
    a = fmaf(w3, bf2f(xt[ll+3][dloc]), a);
    ot[dloc][ll] = silu_f(a);
  }
  __syncthreads();
#pragma unroll
  for (int q = 0; q < 4; ++q) {
    int f4 = q * 256 + tid;
    int dr = f4 >> 4, lc = (f4 & 15) * 4;
    float4 v = make_float4(ot[dr][lc], ot[dr][lc+1], ot[dr][lc+2], ot[dr][lc+3]);
    *(float4*)&xcT[(size_t)(d0 + dr) * L_SEQ + l0 + lc] = v;
  }
}

// ---------------------------------------------------------------------------
// xp partials from xcT: split-K, transposed LDS staging.
// grid = (L/64, KSPLIT).
// ---------------------------------------------------------------------------
__global__ __launch_bounds__(256) void gemm_xp_k(
    const float* __restrict__ xcT, const float* __restrict__ Wxp,
    float* __restrict__ xp_part) {
  const int L0   = blockIdx.x * 64;
  const int ks   = blockIdx.y;
  const int wv   = threadIdx.x >> 6;
  const int lane = threadIdx.x & 63;
  __shared__ float xcs[64][65];    // [l][k]
  __shared__ float Ws[36][64];
  float acc[9] = {};
  const int kbeg = ks * (DI / KSPLIT);
  const int kend = kbeg + DI / KSPLIT;
  for (int k0 = kbeg; k0 < kend; k0 += 64) {
#pragma unroll
    for (int q = 0; q < 4; ++q) {
      int f4 = q * 256 + threadIdx.x;
      int dr = f4 >> 4;
      int lc = (f4 & 15) * 4;
      float4 v = *(const float4*)&xcT[(size_t)(k0 + dr) * L_SEQ + L0 + lc];
      xcs[lc+0][dr] = v.x; xcs[lc+1][dr] = v.y;
      xcs[lc+2][dr] = v.z; xcs[lc+3][dr] = v.w;
    }
    for (int idx = threadIdx.x; idx < 36 * 16; idx += 256) {
      int j = idx >> 4; int cc = (idx & 15) << 2;
      float4 v = make_float4(0.f, 0.f, 0.f, 0.f);
      if (j < 33) v = *(const float4*)&Wxp[(size_t)j * DI + k0 + cc];
      *(float4*)&Ws[j][cc] = v;
    }
    __syncthreads();
#pragma unroll 4
    for (int kk = 0; kk < 64; kk += 4) {
      float4 wr[9];
#pragma unroll
      for (int jj = 0; jj < 9; ++jj) wr[jj] = *(const float4*)&Ws[wv*9 + jj][kk];
      float a0 = xcs[lane][kk+0], a1 = xcs[lane][kk+1];
      float a2 = xcs[lane][kk+2], a3 = xcs[lane][kk+3];
#pragma unroll
      for (int jj = 0; jj < 9; ++jj) {
        acc[jj] = fmaf(a0, wr[jj].x, acc[jj]);
        acc[jj] = fmaf(a1, wr[jj].y, acc[jj]);
        acc[jj] = fmaf(a2, wr[jj].z, acc[jj]);
        acc[jj] = fmaf(a3, wr[jj].w, acc[jj]);
      }
    }
    __syncthreads();
  }
  const int l = L0 + lane;
#pragma unroll
  for (int jj = 0; jj < 9; ++jj) {
    int j = wv * 9 + jj;
    if (j < 33)
      xp_part[(size_t)ks * L_SEQ * XP_LD + (size_t)l * XP_LD + j] = acc[jj];
  }
}

// ---------------------------------------------------------------------------
// Reduce split-K partials: xp = sum_ks xp_part[ks].
// ---------------------------------------------------------------------------
__global__ __launch_bounds__(256) void reduce_xp_k(
    const float* __restrict__ part, float* __restrict__ xp) {
  int i = blockIdx.x * 256 + threadIdx.x;
  float s = 0.f;
#pragma unroll
  for (int ks = 0; ks < KSPLIT; ++ks)
    s += part[(size_t)ks * L_SEQ * XP_LD + i];
  xp[i] = s;
}

// ---------------------------------------------------------------------------
// Scan staging helpers (64-d blocks).
// xps row = [B 0..15 | C 16..31 | dtr 32], stride 36.
// ---------------------------------------------------------------------------
__device__ __forceinline__ void stage_xps(
    float (*xps)[36], const float* __restrict__ xp, int l0, int tid) {
  for (int idx = tid; idx < LC * 33; idx += 256) {
    int rr = idx / 33, j = idx - rr * 33;
    int col = (j == 0) ? 32 : j - 1;
    xps[rr][col] = xp[(size_t)(l0 + rr) * XP_LD + j];
  }
}
// xcs[64 d][LC t] (pad 33): 512 float4, 2 rounds.
__device__ __forceinline__ void stage_xcs64(
    float (*xcs)[LC + 1], const float* __restrict__ xcT, int d0, int l0, int tid) {
#pragma unroll
  for (int q = 0; q < 2; ++q) {
    int f4  = q * 256 + tid;
    int row = f4 >> 3;
    int col = (f4 & 7) * 4;
    float4 v = *(const float4*)&xcT[(size_t)(d0 + row) * L_SEQ + l0 + col];
    xcs[row][col+0] = v.x; xcs[row][col+1] = v.y;
    xcs[row][col+2] = v.z; xcs[row][col+3] = v.w;
  }
}
// dts[t][d]: direct from global xp (col 0 = dt_r; broadcast loads), no xps dep.
__device__ __forceinline__ void stage_dts64(
    float (*dts)[64], const float* __restrict__ xp,
    const float* __restrict__ dtw, const float* __restrict__ dtb,
    int d0, int l0, int tid) {
  int dd = tid & 63;
  int tb = (tid >> 6) * 8;
  float wv = dtw[d0 + dd], bv = dtb[d0 + dd];
#pragma unroll
  for (int j = 0; j < 8; ++j)
    dts[tb + j][dd] = softplus_f(fmaf(xp[(size_t)(l0 + tb + j) * XP_LD], wv, bv));
}

// ---------------------------------------------------------------------------
// Scan phase A: local scan from h=0, n-split x4 (4 states/thread).
// grid = (DI/64, NCHUNK), 256 thr = 64 d x 4 n-quads.
// ---------------------------------------------------------------------------
__global__ __launch_bounds__(256, 4) void scan_partial_k(
    const float* __restrict__ xcT, const float* __restrict__ xp,
    const float* __restrict__ dtw, const float* __restrict__ dtb,
    const float* __restrict__ A_log,
    float* __restrict__ P, float* __restrict__ Q) {
  const int tid = threadIdx.x;
  const int dl  = tid >> 2;          // 0..63
  const int nq  = (tid & 3) * 4;     // 0,4,8,12
  const int d0  = blockIdx.x * 64;
  const int d   = d0 + dl;
  const int c   = blockIdx.y;
  const int l0  = c * LC;
  __shared__ float xps[LC][36];
  __shared__ float xcs[64][LC + 1];
  __shared__ float dts[LC][64];
  stage_xps(xps, xp, l0, tid);
  stage_xcs64(xcs, xcT, d0, l0, tid);
  stage_dts64(dts, xp, dtw, dtb, d0, l0, tid);

  float4 Av = *(const float4*)&A_log[(size_t)d * NST + nq];
  float Ad2[4] = { -__expf(Av.x) * LOG2E, -__expf(Av.y) * LOG2E,
                   -__expf(Av.z) * LOG2E, -__expf(Av.w) * LOG2E };
  float h[4] = {0.f, 0.f, 0.f, 0.f};
  float sumdt = 0.f;
  __syncthreads();
#pragma unroll 4
  for (int t = 0; t < LC; ++t) {
    float dt  = dts[t][dl];
    sumdt += dt;
    float dtx = dt * xcs[dl][t];
    f32x4 B = *(const f32x4*)&xps[t][nq];
#pragma unroll
    for (int n = 0; n < 4; ++n) {
      float da = exp2f(dt * Ad2[n]);
      h[n] = fmaf(da, h[n], dtx * B[n]);
    }
  }
  size_t base = ((size_t)c * DI + d) * NST + nq;
  *(float4*)&P[base] = make_float4(exp2f(sumdt * Ad2[0]), exp2f(sumdt * Ad2[1]),
                                   exp2f(sumdt * Ad2[2]), exp2f(sumdt * Ad2[3]));
  *(float4*)&Q[base] = make_float4(h[0], h[1], h[2], h[3]);
}

// ---------------------------------------------------------------------------
// Scan phase B: sequential prefix over chunks, thread per (d, n4).
// QHs transformed IN PLACE: Q[c] -> h_start[c].
// ---------------------------------------------------------------------------
__global__ __launch_bounds__(256) void scan_prefix_k(
    const float* __restrict__ P, float* __restrict__ QHs) {
  const int g = blockIdx.x * 256 + threadIdx.x;
  const int d = g >> 2;
  const int q = (g & 3) << 2;
  float4 h = make_float4(0.f, 0.f, 0.f, 0.f);
#pragma unroll 8
  for (int c = 0; c < NCHUNK; ++c) {
    size_t base = ((size_t)c * DI + d) * NST + q;
    float4 pv = *(const float4*)&P[base];
    float4 qv = *(const float4*)&QHs[base];
    *(float4*)&QHs[base] = h;
    h.x = fmaf(pv.x, h.x, qv.x);
    h.y = fmaf(pv.y, h.y, qv.y);
    h.z = fmaf(pv.z, h.z, qv.z);
    h.w = fmaf(pv.w, h.w, qv.w);
  }
}

// ---------------------------------------------------------------------------
// Scan phase C: seeded re-scan, n-split x4; y reduced via shfl_xor(1)+(2).
// grid = (DI/64, NCHUNK), 256 thr.
// ---------------------------------------------------------------------------
__global__ __launch_bounds__(256, 4) void scan_final_k(
    const float* __restrict__ xcT, const float* __restrict__ xp,
    const float* __restrict__ dtw, const float* __restrict__ dtb,
    const float* __restrict__ A_log, const float* __restrict__ Dp,
    const float* __restrict__ Hs, const ushort* __restrict__ xzb,
    ushort* __restrict__ ys) {
  const int tid = threadIdx.x;
  const int dl  = tid >> 2;
  const int nq  = (tid & 3) * 4;
  const int d0  = blockIdx.x * 64;
  const int d   = d0 + dl;
  const int c   = blockIdx.y;
  const int l0  = c * LC;
  __shared__ float  xps[LC][36];
  __shared__ float  xcs[64][LC + 1];
  __shared__ float  dts[LC][64];
  __shared__ ushort zs[LC][64];     // bf16, linear for global_load_lds
  {
    int id = tid;                   // 256 chunks of 16B = 32 t x 8
    int t  = id >> 3;
    int c8 = (id & 7) * 8;
    gload_lds16(xzb + (size_t)(l0 + t) * 4096 + 2048 + d0 + c8,
                (char*)zs + id * 16);
  }
  stage_xps(xps, xp, l0, tid);
  stage_xcs64(xcs, xcT, d0, l0, tid);
  stage_dts64(dts, xp, dtw, dtb, d0, l0, tid);

  float4 Av = *(const float4*)&A_log[(size_t)d * NST + nq];
  float Ad2[4] = { -__expf(Av.x) * LOG2E, -__expf(Av.y) * LOG2E,
                   -__expf(Av.z) * LOG2E, -__expf(Av.w) * LOG2E };
  const float Dd = Dp[d];
  float h[4];
  size_t hb = ((size_t)c * DI + d) * NST + nq;
  *(float4*)&h[0] = *(const float4*)&Hs[hb];
  __syncthreads();    // drains gload_lds (vmcnt) + LDS staging
#pragma unroll 4
  for (int t = 0; t < LC; ++t) {
    const int l = l0 + t;
    float dt  = dts[t][dl];
    float xcv = xcs[dl][t];
    float dtx = dt * xcv;
    f32x4 B = *(const f32x4*)&xps[t][nq];
    f32x4 C = *(const f32x4*)&xps[t][16 + nq];
    float y = 0.f;
#pragma unroll
    for (int n = 0; n < 4; ++n) {
      float da = exp2f(dt * Ad2[n]);
      h[n] = fmaf(da, h[n], dtx * B[n]);
      y = fmaf(h[n], C[n], y);
    }
    y += __shfl_xor(y, 1);
    y += __shfl_xor(y, 2);
    if ((tid & 3) == 0) {
      y = fmaf(xcv, Dd, y);
      ys[(size_t)l * DI + d] = f2bf(y * silu_f(bf2f(zs[t][dl])));
    }
  }
}

// ---------------------------------------------------------------------------
extern "C" void kernel_launch(void* const* d_in, const int* in_sizes, int n_in,
                              void* d_out, int out_size, void* d_ws, size_t ws_size,
                              hipStream_t stream) {
  const float* x    = (const float*)d_in[0];
  const float* W1   = (const float*)d_in[1];
  const float* cw   = (const float*)d_in[2];
  const float* cb   = (const float*)d_in[3];
  const float* Wxp  = (const float*)d_in[4];
  const float* dtw  = (const float*)d_in[5];
  const float* dtb  = (const float*)d_in[6];
  const float* Alog = (const float*)d_in[7];
  const float* Dp   = (const float*)d_in[8];
  const float* Wout = (const float*)d_in[9];
  float* out = (float*)d_out;

  char* w = (char*)d_ws;
  ushort* xz_bf   = (ushort*)w;                   // [0, 16777216)  (L,4096) bf16
  float*  xcT     = (float*)(w + 16777216);       // [16777216, 33554432)  (d,l) f32
  // region C [33554432, 50331648): x_bf+W1_bf early; P+QHs after GEMM1
  ushort* x_bf    = (ushort*)(w + 33554432);      //  4 MiB
  ushort* W1_bf   = (ushort*)(w + 37748736);      //  8 MiB
  float*  P       = (float*)(w + 33554432);       //  8,388,608 B
  float*  QHs     = (float*)(w + 41943040);       //  8,388,608 B
  // persistent tail
  float*  xp      = (float*)(w + 50331648);       //    294,912 B
  ushort* Wout_bf = (ushort*)(w + 50626560);      //  4 MiB
  ushort* ys_bf   = (ushort*)(w + 54820864);      //  8 MiB (xp_part aliases early)
  float*  xp_part = (float*)(w + 54820864);       //  2,359,296 B, dead pre-scan_final
  // total = 63,209,472 B

  // 0. input fp32 -> bf16
  cvt_bf16_k<<<2048, 256, 0, stream>>>(x,    x_bf,    2048*1024/4);
  cvt_bf16_k<<<4096, 256, 0, stream>>>(W1,   W1_bf,   4096*1024/4);
  cvt_bf16_k<<<2048, 256, 0, stream>>>(Wout, Wout_bf, 1024*2048/4);
  // 1. xz = x @ in_proj_w^T  (bf16 out)
  gemm_mfma_bf16<4, true><<<dim3(4096/128, 2048/128), 256, 0, stream>>>(
      x_bf, W1_bf, xz_bf, DM, 4096);
  // 2. fused conv + silu + transpose -> xcT (d,l)
  conv_silu_T_k<<<dim3(DI/64, L_SEQ/64), 256, 0, stream>>>(xz_bf, cw, cb, xcT);
  // 3. xp = xc @ x_proj_w^T  (split-K from xcT + reduce)
  gemm_xp_k<<<dim3(L_SEQ/64, KSPLIT), 256, 0, stream>>>(xcT, Wxp, xp_part);
  reduce_xp_k<<<L_SEQ*XP_LD/256, 256, 0, stream>>>(xp_part, xp);
  // 4. chunked selective scan (n-split x4)
  scan_partial_k<<<dim3(DI/64, NCHUNK), 256, 0, stream>>>(xcT, xp, dtw, dtb, Alog, P, QHs);
  scan_prefix_k<<<DI*NST/4/256, 256, 0, stream>>>(P, QHs);
  scan_final_k<<<dim3(DI/64, NCHUNK), 256, 0, stream>>>(xcT, xp, dtw, dtb, Alog, Dp, QHs, xz_bf, ys_bf);
  // 5. out = ys @ out_proj_w^T  (fp32 out)
  gemm_mfma_bf16<2, false><<<dim3(1024/128, 2048/64), 256, 0, stream>>>(
      ys_bf, Wout_bf, out, DI, 1024);
}

// Round 12
// 257.587 us; speedup vs baseline: 1.6681x; 1.0223x over previous
//
#include <hip/hip_runtime.h>
#include <math.h>

#define L_SEQ   2048
#define DM      1024
#define DI      2048
#define NST     16
#define LC      32      // chunk length for scan
#define NCHUNK  64      // L_SEQ / LC
#define XP_LD   36      // padded leading dim for xp (33 cols)
#define KSPLIT  8       // K-splits for gemm_xp
#define LOG2E   1.44269504f

typedef short s16x8 __attribute__((ext_vector_type(8)));
typedef unsigned short u16x8 __attribute__((ext_vector_type(8)));
typedef float f32x4 __attribute__((ext_vector_type(4)));

__device__ __forceinline__ float silu_f(float x) {
  return x / (1.0f + __expf(-x));
}
// fast softplus (arg regime safe; threshold 0.155 >> err)
__device__ __forceinline__ float softplus_f(float x) {
  return x > 20.0f ? x : __logf(1.0f + __expf(x));
}
__device__ __forceinline__ ushort f2bf(float f) {
  unsigned int u = __float_as_uint(f);
  unsigned int r = (u + 0x7fffu + ((u >> 16) & 1u)) >> 16;
  return (ushort)r;
}
__device__ __forceinline__ float bf2f(ushort u) {
  return __uint_as_float((unsigned int)u << 16);
}
__device__ __forceinline__ void gload_lds16(const void* g, void* lds) {
  __builtin_amdgcn_global_load_lds(
      (const __attribute__((address_space(1))) unsigned int*)g,
      (__attribute__((address_space(3))) unsigned int*)lds,
      16, 0, 0);
}

// ---------------------------------------------------------------------------
// Fused fp32 -> bf16 conversion of all three weight/input tensors (1 launch).
// Ranges (in float4): x 0..524288, W1 ..1572864, Wout ..2097152.
// ---------------------------------------------------------------------------
__global__ __launch_bounds__(256) void cvt3_k(
    const float* __restrict__ x, const float* __restrict__ W1,
    const float* __restrict__ Wout,
    ushort* __restrict__ x_bf, ushort* __restrict__ W1_bf,
    ushort* __restrict__ Wout_bf) {
  int i = blockIdx.x * 256 + threadIdx.x;
  const float* src; ushort* dst; int off;
  if (i < 524288)        { src = x;    dst = x_bf;    off = i; }
  else if (i < 1572864)  { src = W1;   dst = W1_bf;   off = i - 524288; }
  else                   { src = Wout; dst = Wout_bf; off = i - 1572864; }
  float4 v = ((const float4*)src)[off];
  ushort4 o;
  o.x = f2bf(v.x); o.y = f2bf(v.y); o.z = f2bf(v.z); o.w = f2bf(v.w);
  ((ushort4*)dst)[off] = o;
}

// ---------------------------------------------------------------------------
// bf16 MFMA GEMM: C = A(MxK,row) * B(NxK,row)^T.  Output fp32 or bf16.
// BK=64 (2 MFMA sub-steps per staging round -> half the barriers).
// 4 waves (2x2), BM = MFRAG*32, BN = 128.  grid = (N/128, M/BM).
// ---------------------------------------------------------------------------
template <int MFRAG, bool BF16OUT>
__global__ __launch_bounds__(256) void gemm_mfma_bf16(
    const ushort* __restrict__ A, const ushort* __restrict__ B,
    void* __restrict__ Cv, int K, int ldc) {
  constexpr int BM = MFRAG * 32;
  __shared__ ushort As[BM * 64];
  __shared__ ushort Bs[128 * 64];
  const int tid  = threadIdx.x;
  const int lane = tid & 63;
  const int wv   = tid >> 6;
  const int wr   = wv >> 1;
  const int wc   = wv & 1;
  const int m0 = blockIdx.y * BM;
  const int n0 = blockIdx.x * 128;

  f32x4 acc[MFRAG][4] = {};

  for (int k0 = 0; k0 < K; k0 += 64) {
    __syncthreads();
    // stage A tile: BM rows x 64 cols bf16 = BM*8 chunks of 16B
#pragma unroll
    for (int q = 0; q < BM / 32; ++q) {
      int id  = q * 256 + tid;
      int row = id >> 3;
      gload_lds16(A + (size_t)(m0 + row) * K + k0 + (id & 7) * 8,
                  (char*)As + id * 16);
    }
    // stage B tile: 128 rows x 64 cols = 1024 chunks
#pragma unroll
    for (int q = 0; q < 4; ++q) {
      int id  = q * 256 + tid;
      int row = id >> 3;
      gload_lds16(B + (size_t)(n0 + row) * K + k0 + (id & 7) * 8,
                  (char*)Bs + id * 16);
    }
    __syncthreads();   // drains vmcnt before reads

#pragma unroll
    for (int s = 0; s < 2; ++s) {
      s16x8 af[MFRAG], bfr[4];
#pragma unroll
      for (int m = 0; m < MFRAG; ++m)
        af[m] = *(const s16x8*)&As[(wr * MFRAG * 16 + m * 16 + (lane & 15)) * 64
                                    + s * 32 + (lane >> 4) * 8];
#pragma unroll
      for (int n = 0; n < 4; ++n)
        bfr[n] = *(const s16x8*)&Bs[(wc * 64 + n * 16 + (lane & 15)) * 64
                                     + s * 32 + (lane >> 4) * 8];
#pragma unroll
      for (int m = 0; m < MFRAG; ++m)
#pragma unroll
        for (int n = 0; n < 4; ++n)
          acc[m][n] = __builtin_amdgcn_mfma_f32_16x16x32_bf16(af[m], bfr[n], acc[m][n], 0, 0, 0);
    }
  }
  // epilogue: C/D layout col=lane&15, row=(lane>>4)*4+reg  [m89-verified]
  const int cr = (lane >> 4) * 4;
  const int cc = lane & 15;
#pragma unroll
  for (int m = 0; m < MFRAG; ++m) {
    int gr0 = m0 + wr * MFRAG * 16 + m * 16 + cr;
#pragma unroll
    for (int n = 0; n < 4; ++n) {
      int gc = n0 + wc * 64 + n * 16 + cc;
#pragma unroll
      for (int r = 0; r < 4; ++r) {
        if constexpr (BF16OUT)
          ((ushort*)Cv)[(size_t)(gr0 + r) * ldc + gc] = f2bf(acc[m][n][r]);
        else
          ((float*)Cv)[(size_t)(gr0 + r) * ldc + gc] = acc[m][n][r];
      }
    }
  }
}

// ---------------------------------------------------------------------------
// Fused depthwise conv (D_CONV=4) + bias + silu + transpose.
// Reads xz bf16 (L,4096) x_ssm half; writes xcT fp32 (d,l) coalescedly.
// grid = (DI/64, L/64), 256 thr.
// ---------------------------------------------------------------------------
__global__ __launch_bounds__(256) void conv_silu_T_k(
    const ushort* __restrict__ xzb, const float* __restrict__ cw,
    const float* __restrict__ cb, float* __restrict__ xcT) {
  const int d0  = blockIdx.x * 64;
  const int l0  = blockIdx.y * 64;
  const int tid = threadIdx.x;
  __shared__ ushort xt[67][64];   // rows l0-3 .. l0+63
  __shared__ float  ot[64][65];   // [d][l] out tile
#pragma unroll
  for (int q = 0; q < 3; ++q) {
    int id = q * 256 + tid;
    if (id < 67 * 8) {
      int row = id >> 3, c8 = (id & 7) * 8;
      int l = l0 - 3 + row;
      u16x8 v = (u16x8)(ushort)0;
      if (l >= 0)
        v = *(const u16x8*)&xzb[(size_t)l * 4096 + d0 + c8];
      *(u16x8*)&xt[row][c8] = v;
    }
  }
  __syncthreads();
  const int dloc = tid & 63;
  const int d    = d0 + dloc;
  const float w0 = cw[d*4+0], w1 = cw[d*4+1], w2 = cw[d*4+2], w3 = cw[d*4+3];
  const float bb = cb[d];
  const int lb = (tid >> 6) * 16;
#pragma unroll
  for (int j = 0; j < 16; ++j) {
    int ll = lb + j;
    float a = bb;
    a = fmaf(w0, bf2f(xt[ll+0][dloc]), a);
    a = fmaf(w1, bf2f(xt[ll+1][dloc]), a);
    a = fmaf(w2, bf2f(xt[ll+2][dloc]), a);
    a = fmaf(w3, bf2f(xt[ll+3][dloc]), a);
    ot[dloc][ll] = silu_f(a);
  }
  __syncthreads();
#pragma unroll
  for (int q = 0; q < 4; ++q) {
    int f4 = q * 256 + tid;
    int dr = f4 >> 4, lc = (f4 & 15) * 4;
    float4 v = make_float4(ot[dr][lc], ot[dr][lc+1], ot[dr][lc+2], ot[dr][lc+3]);
    *(float4*)&xcT[(size_t)(d0 + dr) * L_SEQ + l0 + lc] = v;
  }
}

// ---------------------------------------------------------------------------
// xp partials from xcT: split-K, transposed LDS staging.
// grid = (L/64, KSPLIT).
// ---------------------------------------------------------------------------
__global__ __launch_bounds__(256) void gemm_xp_k(
    const float* __restrict__ xcT, const float* __restrict__ Wxp,
    float* __restrict__ xp_part) {
  const int L0   = blockIdx.x * 64;
  const int ks   = blockIdx.y;
  const int wv   = threadIdx.x >> 6;
  const int lane = threadIdx.x & 63;
  __shared__ float xcs[64][65];    // [l][k]
  __shared__ float Ws[36][64];
  float acc[9] = {};
  const int kbeg = ks * (DI / KSPLIT);
  const int kend = kbeg + DI / KSPLIT;
  for (int k0 = kbeg; k0 < kend; k0 += 64) {
#pragma unroll
    for (int q = 0; q < 4; ++q) {
      int f4 = q * 256 + threadIdx.x;
      int dr = f4 >> 4;
      int lc = (f4 & 15) * 4;
      float4 v = *(const float4*)&xcT[(size_t)(k0 + dr) * L_SEQ + L0 + lc];
      xcs[lc+0][dr] = v.x; xcs[lc+1][dr] = v.y;
      xcs[lc+2][dr] = v.z; xcs[lc+3][dr] = v.w;
    }
    for (int idx = threadIdx.x; idx < 36 * 16; idx += 256) {
      int j = idx >> 4; int cc = (idx & 15) << 2;
      float4 v = make_float4(0.f, 0.f, 0.f, 0.f);
      if (j < 33) v = *(const float4*)&Wxp[(size_t)j * DI + k0 + cc];
      *(float4*)&Ws[j][cc] = v;
    }
    __syncthreads();
#pragma unroll 4
    for (int kk = 0; kk < 64; kk += 4) {
      float4 wr[9];
#pragma unroll
      for (int jj = 0; jj < 9; ++jj) wr[jj] = *(const float4*)&Ws[wv*9 + jj][kk];
      float a0 = xcs[lane][kk+0], a1 = xcs[lane][kk+1];
      float a2 = xcs[lane][kk+2], a3 = xcs[lane][kk+3];
#pragma unroll
      for (int jj = 0; jj < 9; ++jj) {
        acc[jj] = fmaf(a0, wr[jj].x, acc[jj]);
        acc[jj] = fmaf(a1, wr[jj].y, acc[jj]);
        acc[jj] = fmaf(a2, wr[jj].z, acc[jj]);
        acc[jj] = fmaf(a3, wr[jj].w, acc[jj]);
      }
    }
    __syncthreads();
  }
  const int l = L0 + lane;
#pragma unroll
  for (int jj = 0; jj < 9; ++jj) {
    int j = wv * 9 + jj;
    if (j < 33)
      xp_part[(size_t)ks * L_SEQ * XP_LD + (size_t)l * XP_LD + j] = acc[jj];
  }
}

// ---------------------------------------------------------------------------
// Reduce split-K partials: xp = sum_ks xp_part[ks].
// ---------------------------------------------------------------------------
__global__ __launch_bounds__(256) void reduce_xp_k(
    const float* __restrict__ part, float* __restrict__ xp) {
  int i = blockIdx.x * 256 + threadIdx.x;
  float s = 0.f;
#pragma unroll
  for (int ks = 0; ks < KSPLIT; ++ks)
    s += part[(size_t)ks * L_SEQ * XP_LD + i];
  xp[i] = s;
}

// ---------------------------------------------------------------------------
// Scan staging helpers (64-d blocks).
// xps row = [B 0..15 | C 16..31 | dtr 32], stride 36.
// ---------------------------------------------------------------------------
__device__ __forceinline__ void stage_xps(
    float (*xps)[36], const float* __restrict__ xp, int l0, int tid) {
  for (int idx = tid; idx < LC * 33; idx += 256) {
    int rr = idx / 33, j = idx - rr * 33;
    int col = (j == 0) ? 32 : j - 1;
    xps[rr][col] = xp[(size_t)(l0 + rr) * XP_LD + j];
  }
}
// xcs[64 d][LC t] (pad 33): 512 float4, 2 rounds.
__device__ __forceinline__ void stage_xcs64(
    float (*xcs)[LC + 1], const float* __restrict__ xcT, int d0, int l0, int tid) {
#pragma unroll
  for (int q = 0; q < 2; ++q) {
    int f4  = q * 256 + tid;
    int row = f4 >> 3;
    int col = (f4 & 7) * 4;
    float4 v = *(const float4*)&xcT[(size_t)(d0 + row) * L_SEQ + l0 + col];
    xcs[row][col+0] = v.x; xcs[row][col+1] = v.y;
    xcs[row][col+2] = v.z; xcs[row][col+3] = v.w;
  }
}
// dts[t][d]: direct from global xp (col 0 = dt_r; broadcast loads), no xps dep.
__device__ __forceinline__ void stage_dts64(
    float (*dts)[64], const float* __restrict__ xp,
    const float* __restrict__ dtw, const float* __restrict__ dtb,
    int d0, int l0, int tid) {
  int dd = tid & 63;
  int tb = (tid >> 6) * 8;
  float wv = dtw[d0 + dd], bv = dtb[d0 + dd];
#pragma unroll
  for (int j = 0; j < 8; ++j)
    dts[tb + j][dd] = softplus_f(fmaf(xp[(size_t)(l0 + tb + j) * XP_LD], wv, bv));
}

// ---------------------------------------------------------------------------
// Scan phase A: local scan from h=0, n-split x4 (4 states/thread).
// grid = (DI/64, NCHUNK), 256 thr = 64 d x 4 n-quads.
// ---------------------------------------------------------------------------
__global__ __launch_bounds__(256, 4) void scan_partial_k(
    const float* __restrict__ xcT, const float* __restrict__ xp,
    const float* __restrict__ dtw, const float* __restrict__ dtb,
    const float* __restrict__ A_log,
    float* __restrict__ P, float* __restrict__ Q) {
  const int tid = threadIdx.x;
  const int dl  = tid >> 2;          // 0..63
  const int nq  = (tid & 3) * 4;     // 0,4,8,12
  const int d0  = blockIdx.x * 64;
  const int d   = d0 + dl;
  const int c   = blockIdx.y;
  const int l0  = c * LC;
  __shared__ float xps[LC][36];
  __shared__ float xcs[64][LC + 1];
  __shared__ float dts[LC][64];
  stage_xps(xps, xp, l0, tid);
  stage_xcs64(xcs, xcT, d0, l0, tid);
  stage_dts64(dts, xp, dtw, dtb, d0, l0, tid);

  float4 Av = *(const float4*)&A_log[(size_t)d * NST + nq];
  float Ad2[4] = { -__expf(Av.x) * LOG2E, -__expf(Av.y) * LOG2E,
                   -__expf(Av.z) * LOG2E, -__expf(Av.w) * LOG2E };
  float h[4] = {0.f, 0.f, 0.f, 0.f};
  float sumdt = 0.f;
  __syncthreads();
#pragma unroll 4
  for (int t = 0; t < LC; ++t) {
    float dt  = dts[t][dl];
    sumdt += dt;
    float dtx = dt * xcs[dl][t];
    f32x4 B = *(const f32x4*)&xps[t][nq];
#pragma unroll
    for (int n = 0; n < 4; ++n) {
      float da = exp2f(dt * Ad2[n]);
      h[n] = fmaf(da, h[n], dtx * B[n]);
    }
  }
  size_t base = ((size_t)c * DI + d) * NST + nq;
  *(float4*)&P[base] = make_float4(exp2f(sumdt * Ad2[0]), exp2f(sumdt * Ad2[1]),
                                   exp2f(sumdt * Ad2[2]), exp2f(sumdt * Ad2[3]));
  *(float4*)&Q[base] = make_float4(h[0], h[1], h[2], h[3]);
}

// ---------------------------------------------------------------------------
// Scan phase B: sequential prefix over chunks, one scalar chain per (d, n).
// QHs transformed IN PLACE: Q[c] -> h_start[c].  32768 threads, 128 blocks.
// ---------------------------------------------------------------------------
__global__ __launch_bounds__(256) void scan_prefix_k(
    const float* __restrict__ P, float* __restrict__ QHs) {
  const int g = blockIdx.x * 256 + threadIdx.x;   // 0..32767
  const int d = g >> 4;
  const int n = g & 15;
  float h = 0.f;
#pragma unroll 8
  for (int c = 0; c < NCHUNK; ++c) {
    size_t base = ((size_t)c * DI + d) * NST + n;
    float pv = P[base];
    float qv = QHs[base];
    QHs[base] = h;
    h = fmaf(pv, h, qv);
  }
}

// ---------------------------------------------------------------------------
// Scan phase C: seeded re-scan, n-split x4; y reduced via shfl_xor(1)+(2).
// grid = (DI/64, NCHUNK), 256 thr.
// ---------------------------------------------------------------------------
__global__ __launch_bounds__(256, 4) void scan_final_k(
    const float* __restrict__ xcT, const float* __restrict__ xp,
    const float* __restrict__ dtw, const float* __restrict__ dtb,
    const float* __restrict__ A_log, const float* __restrict__ Dp,
    const float* __restrict__ Hs, const ushort* __restrict__ xzb,
    ushort* __restrict__ ys) {
  const int tid = threadIdx.x;
  const int dl  = tid >> 2;
  const int nq  = (tid & 3) * 4;
  const int d0  = blockIdx.x * 64;
  const int d   = d0 + dl;
  const int c   = blockIdx.y;
  const int l0  = c * LC;
  __shared__ float  xps[LC][36];
  __shared__ float  xcs[64][LC + 1];
  __shared__ float  dts[LC][64];
  __shared__ ushort zs[LC][64];     // bf16, linear for global_load_lds
  {
    int id = tid;                   // 256 chunks of 16B = 32 t x 8
    int t  = id >> 3;
    int c8 = (id & 7) * 8;
    gload_lds16(xzb + (size_t)(l0 + t) * 4096 + 2048 + d0 + c8,
                (char*)zs + id * 16);
  }
  stage_xps(xps, xp, l0, tid);
  stage_xcs64(xcs, xcT, d0, l0, tid);
  stage_dts64(dts, xp, dtw, dtb, d0, l0, tid);

  float4 Av = *(const float4*)&A_log[(size_t)d * NST + nq];
  float Ad2[4] = { -__expf(Av.x) * LOG2E, -__expf(Av.y) * LOG2E,
                   -__expf(Av.z) * LOG2E, -__expf(Av.w) * LOG2E };
  const float Dd = Dp[d];
  float h[4];
  size_t hb = ((size_t)c * DI + d) * NST + nq;
  *(float4*)&h[0] = *(const float4*)&Hs[hb];
  __syncthreads();    // drains gload_lds (vmcnt) + LDS staging
#pragma unroll 4
  for (int t = 0; t < LC; ++t) {
    const int l = l0 + t;
    float dt  = dts[t][dl];
    float xcv = xcs[dl][t];
    float dtx = dt * xcv;
    f32x4 B = *(const f32x4*)&xps[t][nq];
    f32x4 C = *(const f32x4*)&xps[t][16 + nq];
    float y = 0.f;
#pragma unroll
    for (int n = 0; n < 4; ++n) {
      float da = exp2f(dt * Ad2[n]);
      h[n] = fmaf(da, h[n], dtx * B[n]);
      y = fmaf(h[n], C[n], y);
    }
    y += __shfl_xor(y, 1);
    y += __shfl_xor(y, 2);
    if ((tid & 3) == 0) {
      y = fmaf(xcv, Dd, y);
      ys[(size_t)l * DI + d] = f2bf(y * silu_f(bf2f(zs[t][dl])));
    }
  }
}

// ---------------------------------------------------------------------------
extern "C" void kernel_launch(void* const* d_in, const int* in_sizes, int n_in,
                              void* d_out, int out_size, void* d_ws, size_t ws_size,
                              hipStream_t stream) {
  const float* x    = (const float*)d_in[0];
  const float* W1   = (const float*)d_in[1];
  const float* cw   = (const float*)d_in[2];
  const float* cb   = (const float*)d_in[3];
  const float* Wxp  = (const float*)d_in[4];
  const float* dtw  = (const float*)d_in[5];
  const float* dtb  = (const float*)d_in[6];
  const float* Alog = (const float*)d_in[7];
  const float* Dp   = (const float*)d_in[8];
  const float* Wout = (const float*)d_in[9];
  float* out = (float*)d_out;

  char* w = (char*)d_ws;
  ushort* xz_bf   = (ushort*)w;                   // [0, 16777216)  (L,4096) bf16
  float*  xcT     = (float*)(w + 16777216);       // [16777216, 33554432)  (d,l) f32
  // region C [33554432, 50331648): x_bf+W1_bf early; P+QHs after GEMM1
  ushort* x_bf    = (ushort*)(w + 33554432);      //  4 MiB
  ushort* W1_bf   = (ushort*)(w + 37748736);      //  8 MiB
  float*  P       = (float*)(w + 33554432);       //  8,388,608 B
  float*  QHs     = (float*)(w + 41943040);       //  8,388,608 B
  // persistent tail
  float*  xp      = (float*)(w + 50331648);       //    294,912 B
  ushort* Wout_bf = (ushort*)(w + 50626560);      //  4 MiB
  ushort* ys_bf   = (ushort*)(w + 54820864);      //  8 MiB (xp_part aliases early)
  float*  xp_part = (float*)(w + 54820864);       //  2,359,296 B, dead pre-scan_final
  // total = 63,209,472 B

  // 0. input fp32 -> bf16 (single fused launch)
  cvt3_k<<<8192, 256, 0, stream>>>(x, W1, Wout, x_bf, W1_bf, Wout_bf);
  // 1. xz = x @ in_proj_w^T  (bf16 out, BK=64)
  gemm_mfma_bf16<4, true><<<dim3(4096/128, 2048/128), 256, 0, stream>>>(
      x_bf, W1_bf, xz_bf, DM, 4096);
  // 2. fused conv + silu + transpose -> xcT (d,l)
  conv_silu_T_k<<<dim3(DI/64, L_SEQ/64), 256, 0, stream>>>(xz_bf, cw, cb, xcT);
  // 3. xp = xc @ x_proj_w^T  (split-K from xcT + reduce)
  gemm_xp_k<<<dim3(L_SEQ/64, KSPLIT), 256, 0, stream>>>(xcT, Wxp, xp_part);
  reduce_xp_k<<<L_SEQ*XP_LD/256, 256, 0, stream>>>(xp_part, xp);
  // 4. chunked selective scan (n-split x4)
  scan_partial_k<<<dim3(DI/64, NCHUNK), 256, 0, stream>>>(xcT, xp, dtw, dtb, Alog, P, QHs);
  scan_prefix_k<<<DI*NST/256, 256, 0, stream>>>(P, QHs);
  scan_final_k<<<dim3(DI/64, NCHUNK), 256, 0, stream>>>(xcT, xp, dtw, dtb, Alog, Dp, QHs, xz_bf, ys_bf);
  // 5. out = ys @ out_proj_w^T  (fp32 out, BK=64)
  gemm_mfma_bf16<2, false><<<dim3(1024/128, 2048/64), 256, 0, stream>>>(
      ys_bf, Wout_bf, out, DI, 1024);
}

// Round 13
// 256.887 us; speedup vs baseline: 1.6727x; 1.0027x over previous
//
#include <hip/hip_runtime.h>
#include <math.h>

#define L_SEQ   2048
#define DM      1024
#define DI      2048
#define NST     16
#define LC      32      // chunk length for scan
#define NCHUNK  64      // L_SEQ / LC
#define XP_LD   36      // padded leading dim for xp (33 cols)
#define KSPLIT  8       // K-splits for gemm_xp
#define LOG2E   1.44269504f

typedef short s16x8 __attribute__((ext_vector_type(8)));
typedef unsigned short u16x8 __attribute__((ext_vector_type(8)));
typedef float f32x4 __attribute__((ext_vector_type(4)));

__device__ __forceinline__ float silu_f(float x) {
  return x / (1.0f + __expf(-x));
}
// fast softplus (arg regime safe; threshold 0.155 >> err)
__device__ __forceinline__ float softplus_f(float x) {
  return x > 20.0f ? x : __logf(1.0f + __expf(x));
}
__device__ __forceinline__ ushort f2bf(float f) {
  unsigned int u = __float_as_uint(f);
  unsigned int r = (u + 0x7fffu + ((u >> 16) & 1u)) >> 16;
  return (ushort)r;
}
__device__ __forceinline__ float bf2f(ushort u) {
  return __uint_as_float((unsigned int)u << 16);
}
__device__ __forceinline__ void gload_lds16(const void* g, void* lds) {
  __builtin_amdgcn_global_load_lds(
      (const __attribute__((address_space(1))) unsigned int*)g,
      (__attribute__((address_space(3))) unsigned int*)lds,
      16, 0, 0);
}

// ---------------------------------------------------------------------------
// Fused fp32 -> bf16 conversion of all three weight/input tensors (1 launch).
// Ranges (in float4): x 0..524288, W1 ..1572864, Wout ..2097152.
// ---------------------------------------------------------------------------
__global__ __launch_bounds__(256) void cvt3_k(
    const float* __restrict__ x, const float* __restrict__ W1,
    const float* __restrict__ Wout,
    ushort* __restrict__ x_bf, ushort* __restrict__ W1_bf,
    ushort* __restrict__ Wout_bf) {
  int i = blockIdx.x * 256 + threadIdx.x;
  const float* src; ushort* dst; int off;
  if (i < 524288)        { src = x;    dst = x_bf;    off = i; }
  else if (i < 1572864)  { src = W1;   dst = W1_bf;   off = i - 524288; }
  else                   { src = Wout; dst = Wout_bf; off = i - 1572864; }
  float4 v = ((const float4*)src)[off];
  ushort4 o;
  o.x = f2bf(v.x); o.y = f2bf(v.y); o.z = f2bf(v.z); o.w = f2bf(v.w);
  ((ushort4*)dst)[off] = o;
}

// ---------------------------------------------------------------------------
// bf16 MFMA GEMM: C = A(MxK,row) * B(NxK,row)^T.  Output fp32 or bf16.
// BK=64 (2 MFMA sub-steps per staging round -> half the barriers).
// 4 waves (2x2), BM = MFRAG*32, BN = 128.  grid = (N/128, M/BM).
// ---------------------------------------------------------------------------
template <int MFRAG, bool BF16OUT>
__global__ __launch_bounds__(256) void gemm_mfma_bf16(
    const ushort* __restrict__ A, const ushort* __restrict__ B,
    void* __restrict__ Cv, int K, int ldc) {
  constexpr int BM = MFRAG * 32;
  __shared__ ushort As[BM * 64];
  __shared__ ushort Bs[128 * 64];
  const int tid  = threadIdx.x;
  const int lane = tid & 63;
  const int wv   = tid >> 6;
  const int wr   = wv >> 1;
  const int wc   = wv & 1;
  const int m0 = blockIdx.y * BM;
  const int n0 = blockIdx.x * 128;

  f32x4 acc[MFRAG][4] = {};

  for (int k0 = 0; k0 < K; k0 += 64) {
    __syncthreads();
#pragma unroll
    for (int q = 0; q < BM / 32; ++q) {
      int id  = q * 256 + tid;
      int row = id >> 3;
      gload_lds16(A + (size_t)(m0 + row) * K + k0 + (id & 7) * 8,
                  (char*)As + id * 16);
    }
#pragma unroll
    for (int q = 0; q < 4; ++q) {
      int id  = q * 256 + tid;
      int row = id >> 3;
      gload_lds16(B + (size_t)(n0 + row) * K + k0 + (id & 7) * 8,
                  (char*)Bs + id * 16);
    }
    __syncthreads();   // drains vmcnt before reads

#pragma unroll
    for (int s = 0; s < 2; ++s) {
      s16x8 af[MFRAG], bfr[4];
#pragma unroll
      for (int m = 0; m < MFRAG; ++m)
        af[m] = *(const s16x8*)&As[(wr * MFRAG * 16 + m * 16 + (lane & 15)) * 64
                                    + s * 32 + (lane >> 4) * 8];
#pragma unroll
      for (int n = 0; n < 4; ++n)
        bfr[n] = *(const s16x8*)&Bs[(wc * 64 + n * 16 + (lane & 15)) * 64
                                     + s * 32 + (lane >> 4) * 8];
#pragma unroll
      for (int m = 0; m < MFRAG; ++m)
#pragma unroll
        for (int n = 0; n < 4; ++n)
          acc[m][n] = __builtin_amdgcn_mfma_f32_16x16x32_bf16(af[m], bfr[n], acc[m][n], 0, 0, 0);
    }
  }
  // epilogue: C/D layout col=lane&15, row=(lane>>4)*4+reg  [m89-verified]
  const int cr = (lane >> 4) * 4;
  const int cc = lane & 15;
#pragma unroll
  for (int m = 0; m < MFRAG; ++m) {
    int gr0 = m0 + wr * MFRAG * 16 + m * 16 + cr;
#pragma unroll
    for (int n = 0; n < 4; ++n) {
      int gc = n0 + wc * 64 + n * 16 + cc;
#pragma unroll
      for (int r = 0; r < 4; ++r) {
        if constexpr (BF16OUT)
          ((ushort*)Cv)[(size_t)(gr0 + r) * ldc + gc] = f2bf(acc[m][n][r]);
        else
          ((float*)Cv)[(size_t)(gr0 + r) * ldc + gc] = acc[m][n][r];
      }
    }
  }
}

// ---------------------------------------------------------------------------
// Fused depthwise conv (D_CONV=4) + bias + silu + transpose.
// Reads xz bf16 (L,4096) x_ssm half; writes xcT *bf16* (d,l) coalescedly.
// grid = (DI/64, L/64), 256 thr.
// ---------------------------------------------------------------------------
__global__ __launch_bounds__(256) void conv_silu_T_k(
    const ushort* __restrict__ xzb, const float* __restrict__ cw,
    const float* __restrict__ cb, ushort* __restrict__ xcT) {
  const int d0  = blockIdx.x * 64;
  const int l0  = blockIdx.y * 64;
  const int tid = threadIdx.x;
  __shared__ ushort xt[67][64];   // rows l0-3 .. l0+63
  __shared__ float  ot[64][65];   // [d][l] out tile
#pragma unroll
  for (int q = 0; q < 3; ++q) {
    int id = q * 256 + tid;
    if (id < 67 * 8) {
      int row = id >> 3, c8 = (id & 7) * 8;
      int l = l0 - 3 + row;
      u16x8 v = (u16x8)(ushort)0;
      if (l >= 0)
        v = *(const u16x8*)&xzb[(size_t)l * 4096 + d0 + c8];
      *(u16x8*)&xt[row][c8] = v;
    }
  }
  __syncthreads();
  const int dloc = tid & 63;
  const int d    = d0 + dloc;
  const float w0 = cw[d*4+0], w1 = cw[d*4+1], w2 = cw[d*4+2], w3 = cw[d*4+3];
  const float bb = cb[d];
  const int lb = (tid >> 6) * 16;
#pragma unroll
  for (int j = 0; j < 16; ++j) {
    int ll = lb + j;
    float a = bb;
    a = fmaf(w0, bf2f(xt[ll+0][dloc]), a);
    a = fmaf(w1, bf2f(xt[ll+1][dloc]), a);
    a = fmaf(w2, bf2f(xt[ll+2][dloc]), a);
    a = fmaf(w3, bf2f(xt[ll+3][dloc]), a);
    ot[dloc][ll] = silu_f(a);
  }
  __syncthreads();
  // bf16 out: 64x64 elems = 512 chunks of 8, 2 rounds, 16B stores
#pragma unroll
  for (int q = 0; q < 2; ++q) {
    int f8 = q * 256 + tid;
    int dr = f8 >> 3, c8 = (f8 & 7) * 8;
    u16x8 o;
#pragma unroll
    for (int i = 0; i < 8; ++i) o[i] = f2bf(ot[dr][c8 + i]);
    *(u16x8*)&xcT[(size_t)(d0 + dr) * L_SEQ + l0 + c8] = o;
  }
}

// ---------------------------------------------------------------------------
// xp partials from bf16 xcT: split-K, transposed LDS staging (fp32 in LDS).
// grid = (L/64, KSPLIT).
// ---------------------------------------------------------------------------
__global__ __launch_bounds__(256) void gemm_xp_k(
    const ushort* __restrict__ xcT, const float* __restrict__ Wxp,
    float* __restrict__ xp_part) {
  const int L0   = blockIdx.x * 64;
  const int ks   = blockIdx.y;
  const int wv   = threadIdx.x >> 6;
  const int lane = threadIdx.x & 63;
  __shared__ float xcs[64][65];    // [l][k]
  __shared__ float Ws[36][64];
  float acc[9] = {};
  const int kbeg = ks * (DI / KSPLIT);
  const int kend = kbeg + DI / KSPLIT;
  for (int k0 = kbeg; k0 < kend; k0 += 64) {
    // stage 64k x 64l from bf16: 512 chunks of 8, 2 rounds
#pragma unroll
    for (int q = 0; q < 2; ++q) {
      int f8 = q * 256 + threadIdx.x;
      int dr = f8 >> 3;              // k row 0..63
      int c8 = (f8 & 7) * 8;         // l col
      u16x8 v = *(const u16x8*)&xcT[(size_t)(k0 + dr) * L_SEQ + L0 + c8];
#pragma unroll
      for (int i = 0; i < 8; ++i) xcs[c8 + i][dr] = bf2f(v[i]);
    }
    for (int idx = threadIdx.x; idx < 36 * 16; idx += 256) {
      int j = idx >> 4; int cc = (idx & 15) << 2;
      float4 v = make_float4(0.f, 0.f, 0.f, 0.f);
      if (j < 33) v = *(const float4*)&Wxp[(size_t)j * DI + k0 + cc];
      *(float4*)&Ws[j][cc] = v;
    }
    __syncthreads();
#pragma unroll 4
    for (int kk = 0; kk < 64; kk += 4) {
      float4 wr[9];
#pragma unroll
      for (int jj = 0; jj < 9; ++jj) wr[jj] = *(const float4*)&Ws[wv*9 + jj][kk];
      float a0 = xcs[lane][kk+0], a1 = xcs[lane][kk+1];
      float a2 = xcs[lane][kk+2], a3 = xcs[lane][kk+3];
#pragma unroll
      for (int jj = 0; jj < 9; ++jj) {
        acc[jj] = fmaf(a0, wr[jj].x, acc[jj]);
        acc[jj] = fmaf(a1, wr[jj].y, acc[jj]);
        acc[jj] = fmaf(a2, wr[jj].z, acc[jj]);
        acc[jj] = fmaf(a3, wr[jj].w, acc[jj]);
      }
    }
    __syncthreads();
  }
  const int l = L0 + lane;
#pragma unroll
  for (int jj = 0; jj < 9; ++jj) {
    int j = wv * 9 + jj;
    if (j < 33)
      xp_part[(size_t)ks * L_SEQ * XP_LD + (size_t)l * XP_LD + j] = acc[jj];
  }
}

// ---------------------------------------------------------------------------
// Reduce split-K partials: xp = sum_ks xp_part[ks].
// ---------------------------------------------------------------------------
__global__ __launch_bounds__(256) void reduce_xp_k(
    const float* __restrict__ part, float* __restrict__ xp) {
  int i = blockIdx.x * 256 + threadIdx.x;
  float s = 0.f;
#pragma unroll
  for (int ks = 0; ks < KSPLIT; ++ks)
    s += part[(size_t)ks * L_SEQ * XP_LD + i];
  xp[i] = s;
}

// ---------------------------------------------------------------------------
// Scan staging helpers (64-d blocks).
// xps row = [B 0..15 | C 16..31 | dtr 32], stride 36.
// ---------------------------------------------------------------------------
__device__ __forceinline__ void stage_xps(
    float (*xps)[36], const float* __restrict__ xp, int l0, int tid) {
  for (int idx = tid; idx < LC * 33; idx += 256) {
    int rr = idx / 33, j = idx - rr * 33;
    int col = (j == 0) ? 32 : j - 1;
    xps[rr][col] = xp[(size_t)(l0 + rr) * XP_LD + j];
  }
}
// xcs[64 d][LC t] fp32 in LDS, staged from bf16 xcT: 256 chunks of 8, 1 round.
__device__ __forceinline__ void stage_xcs64(
    float (*xcs)[LC + 1], const ushort* __restrict__ xcT, int d0, int l0, int tid) {
  int row = tid >> 2;              // 0..63
  int c8  = (tid & 3) * 8;         // 0..24
  u16x8 v = *(const u16x8*)&xcT[(size_t)(d0 + row) * L_SEQ + l0 + c8];
#pragma unroll
  for (int i = 0; i < 8; ++i) xcs[row][c8 + i] = bf2f(v[i]);
}
// dts[t][d]: direct from global xp (col 0 = dt_r; broadcast loads), no xps dep.
__device__ __forceinline__ void stage_dts64(
    float (*dts)[64], const float* __restrict__ xp,
    const float* __restrict__ dtw, const float* __restrict__ dtb,
    int d0, int l0, int tid) {
  int dd = tid & 63;
  int tb = (tid >> 6) * 8;
  float wv = dtw[d0 + dd], bv = dtb[d0 + dd];
#pragma unroll
  for (int j = 0; j < 8; ++j)
    dts[tb + j][dd] = softplus_f(fmaf(xp[(size_t)(l0 + tb + j) * XP_LD], wv, bv));
}

// ---------------------------------------------------------------------------
// Scan phase A: local scan from h=0, n-split x4 (4 states/thread).
// grid = (DI/64, NCHUNK), 256 thr = 64 d x 4 n-quads.
// ---------------------------------------------------------------------------
__global__ __launch_bounds__(256, 4) void scan_partial_k(
    const ushort* __restrict__ xcT, const float* __restrict__ xp,
    const float* __restrict__ dtw, const float* __restrict__ dtb,
    const float* __restrict__ A_log,
    float* __restrict__ P, float* __restrict__ Q) {
  const int tid = threadIdx.x;
  const int dl  = tid >> 2;          // 0..63
  const int nq  = (tid & 3) * 4;     // 0,4,8,12
  const int d0  = blockIdx.x * 64;
  const int d   = d0 + dl;
  const int c   = blockIdx.y;
  const int l0  = c * LC;
  __shared__ float xps[LC][36];
  __shared__ float xcs[64][LC + 1];
  __shared__ float dts[LC][64];
  stage_xps(xps, xp, l0, tid);
  stage_xcs64(xcs, xcT, d0, l0, tid);
  stage_dts64(dts, xp, dtw, dtb, d0, l0, tid);

  float4 Av = *(const float4*)&A_log[(size_t)d * NST + nq];
  float Ad2[4] = { -__expf(Av.x) * LOG2E, -__expf(Av.y) * LOG2E,
                   -__expf(Av.z) * LOG2E, -__expf(Av.w) * LOG2E };
  float h[4] = {0.f, 0.f, 0.f, 0.f};
  float sumdt = 0.f;
  __syncthreads();
#pragma unroll 4
  for (int t = 0; t < LC; ++t) {
    float dt  = dts[t][dl];
    sumdt += dt;
    float dtx = dt * xcs[dl][t];
    f32x4 B = *(const f32x4*)&xps[t][nq];
#pragma unroll
    for (int n = 0; n < 4; ++n) {
      float da = exp2f(dt * Ad2[n]);
      h[n] = fmaf(da, h[n], dtx * B[n]);
    }
  }
  size_t base = ((size_t)c * DI + d) * NST + nq;
  *(float4*)&P[base] = make_float4(exp2f(sumdt * Ad2[0]), exp2f(sumdt * Ad2[1]),
                                   exp2f(sumdt * Ad2[2]), exp2f(sumdt * Ad2[3]));
  *(float4*)&Q[base] = make_float4(h[0], h[1], h[2], h[3]);
}

// ---------------------------------------------------------------------------
// Scan phase B: sequential prefix over chunks, one scalar chain per (d, n).
// QHs transformed IN PLACE: Q[c] -> h_start[c].  32768 threads, 128 blocks.
// ---------------------------------------------------------------------------
__global__ __launch_bounds__(256) void scan_prefix_k(
    const float* __restrict__ P, float* __restrict__ QHs) {
  const int g = blockIdx.x * 256 + threadIdx.x;   // 0..32767
  const int d = g >> 4;
  const int n = g & 15;
  float h = 0.f;
#pragma unroll 8
  for (int c = 0; c < NCHUNK; ++c) {
    size_t base = ((size_t)c * DI + d) * NST + n;
    float pv = P[base];
    float qv = QHs[base];
    QHs[base] = h;
    h = fmaf(pv, h, qv);
  }
}

// ---------------------------------------------------------------------------
// Scan phase C: seeded re-scan, n-split x4; y reduced via shfl_xor(1)+(2).
// grid = (DI/64, NCHUNK), 256 thr.
// ---------------------------------------------------------------------------
__global__ __launch_bounds__(256, 4) void scan_final_k(
    const ushort* __restrict__ xcT, const float* __restrict__ xp,
    const float* __restrict__ dtw, const float* __restrict__ dtb,
    const float* __restrict__ A_log, const float* __restrict__ Dp,
    const float* __restrict__ Hs, const ushort* __restrict__ xzb,
    ushort* __restrict__ ys) {
  const int tid = threadIdx.x;
  const int dl  = tid >> 2;
  const int nq  = (tid & 3) * 4;
  const int d0  = blockIdx.x * 64;
  const int d   = d0 + dl;
  const int c   = blockIdx.y;
  const int l0  = c * LC;
  __shared__ float  xps[LC][36];
  __shared__ float  xcs[64][LC + 1];
  __shared__ float  dts[LC][64];
  __shared__ ushort zs[LC][64];     // bf16, linear for global_load_lds
  {
    int id = tid;                   // 256 chunks of 16B = 32 t x 8
    int t  = id >> 3;
    int c8 = (id & 7) * 8;
    gload_lds16(xzb + (size_t)(l0 + t) * 4096 + 2048 + d0 + c8,
                (char*)zs + id * 16);
  }
  stage_xps(xps, xp, l0, tid);
  stage_xcs64(xcs, xcT, d0, l0, tid);
  stage_dts64(dts, xp, dtw, dtb, d0, l0, tid);

  float4 Av = *(const float4*)&A_log[(size_t)d * NST + nq];
  float Ad2[4] = { -__expf(Av.x) * LOG2E, -__expf(Av.y) * LOG2E,
                   -__expf(Av.z) * LOG2E, -__expf(Av.w) * LOG2E };
  const float Dd = Dp[d];
  float h[4];
  size_t hb = ((size_t)c * DI + d) * NST + nq;
  *(float4*)&h[0] = *(const float4*)&Hs[hb];
  __syncthreads();    // drains gload_lds (vmcnt) + LDS staging
#pragma unroll 4
  for (int t = 0; t < LC; ++t) {
    const int l = l0 + t;
    float dt  = dts[t][dl];
    float xcv = xcs[dl][t];
    float dtx = dt * xcv;
    f32x4 B = *(const f32x4*)&xps[t][nq];
    f32x4 C = *(const f32x4*)&xps[t][16 + nq];
    float y = 0.f;
#pragma unroll
    for (int n = 0; n < 4; ++n) {
      float da = exp2f(dt * Ad2[n]);
      h[n] = fmaf(da, h[n], dtx * B[n]);
      y = fmaf(h[n], C[n], y);
    }
    y += __shfl_xor(y, 1);
    y += __shfl_xor(y, 2);
    if ((tid & 3) == 0) {
      y = fmaf(xcv, Dd, y);
      ys[(size_t)l * DI + d] = f2bf(y * silu_f(bf2f(zs[t][dl])));
    }
  }
}

// ---------------------------------------------------------------------------
extern "C" void kernel_launch(void* const* d_in, const int* in_sizes, int n_in,
                              void* d_out, int out_size, void* d_ws, size_t ws_size,
                              hipStream_t stream) {
  const float* x    = (const float*)d_in[0];
  const float* W1   = (const float*)d_in[1];
  const float* cw   = (const float*)d_in[2];
  const float* cb   = (const float*)d_in[3];
  const float* Wxp  = (const float*)d_in[4];
  const float* dtw  = (const float*)d_in[5];
  const float* dtb  = (const float*)d_in[6];
  const float* Alog = (const float*)d_in[7];
  const float* Dp   = (const float*)d_in[8];
  const float* Wout = (const float*)d_in[9];
  float* out = (float*)d_out;

  char* w = (char*)d_ws;
  ushort* xz_bf   = (ushort*)w;                   // [0, 16777216)  (L,4096) bf16
  ushort* xcT     = (ushort*)(w + 16777216);      // [16777216, 25165824)  (d,l) bf16
  // region C [25165824, 41943040): x_bf+W1_bf early; P+QHs after GEMM1
  ushort* x_bf    = (ushort*)(w + 25165824);      //  4 MiB
  ushort* W1_bf   = (ushort*)(w + 29360128);      //  8 MiB
  float*  P       = (float*)(w + 25165824);       //  8,388,608 B
  float*  QHs     = (float*)(w + 33554432);       //  8,388,608 B
  // persistent tail
  float*  xp      = (float*)(w + 41943040);       //    294,912 B
  ushort* Wout_bf = (ushort*)(w + 42237952);      //  4 MiB
  ushort* ys_bf   = (ushort*)(w + 46432256);      //  8 MiB (xp_part aliases early)
  float*  xp_part = (float*)(w + 46432256);       //  2,359,296 B, dead pre-scan_final
  // total = 54,820,864 B

  // 0. input fp32 -> bf16 (single fused launch)
  cvt3_k<<<8192, 256, 0, stream>>>(x, W1, Wout, x_bf, W1_bf, Wout_bf);
  // 1. xz = x @ in_proj_w^T  (bf16 out, BK=64)
  gemm_mfma_bf16<4, true><<<dim3(4096/128, 2048/128), 256, 0, stream>>>(
      x_bf, W1_bf, xz_bf, DM, 4096);
  // 2. fused conv + silu + transpose -> xcT (d,l) bf16
  conv_silu_T_k<<<dim3(DI/64, L_SEQ/64), 256, 0, stream>>>(xz_bf, cw, cb, xcT);
  // 3. xp = xc @ x_proj_w^T  (split-K from bf16 xcT + reduce)
  gemm_xp_k<<<dim3(L_SEQ/64, KSPLIT), 256, 0, stream>>>(xcT, Wxp, xp_part);
  reduce_xp_k<<<L_SEQ*XP_LD/256, 256, 0, stream>>>(xp_part, xp);
  // 4. chunked selective scan (n-split x4, bf16 xcT)
  scan_partial_k<<<dim3(DI/64, NCHUNK), 256, 0, stream>>>(xcT, xp, dtw, dtb, Alog, P, QHs);
  scan_prefix_k<<<DI*NST/256, 256, 0, stream>>>(P, QHs);
  scan_final_k<<<dim3(DI/64, NCHUNK), 256, 0, stream>>>(xcT, xp, dtw, dtb, Alog, Dp, QHs, xz_bf, ys_bf);
  // 5. out = ys @ out_proj_w^T  (fp32 out, BK=64)
  gemm_mfma_bf16<2, false><<<dim3(1024/128, 2048/64), 256, 0, stream>>>(
      ys_bf, Wout_bf, out, DI, 1024);
}